// Round 2
// baseline (276.065 us; speedup 1.0000x reference)
//
#include <hip/hip_runtime.h>
#include <hip/hip_bf16.h>

typedef __attribute__((ext_vector_type(8))) _Float16 f16x8;
typedef __attribute__((ext_vector_type(4))) float f32x4;
typedef unsigned short u16;
typedef unsigned int u32;

#define S_LEN 2048
#define NH    16
#define DK    64
#define DMODEL 1024
#define LSTR  40   // LDS row stride (f16 elems) for GEMM tiles
#define LOG2E 1.44269504f
#define NTILES (S_LEN / 64)

union F16U { _Float16 h; u16 u; };
__device__ __forceinline__ u16 f2h(float f) {
    F16U v; v.h = (_Float16)f; return v.u;
}

// ------------------------- bias table --------------------------------------
// Integer-exact replica of the reference fp32 bucket math; thresholds
// {12,16,23,32,46,64,91} verified against fp32 log arithmetic.
// NOTE: table is pre-scaled by log2(e) — attn softmax runs in exp2 domain.
__global__ __launch_bounds__(256) void bias_table_kernel(
    const float* __restrict__ rel_emb, float* __restrict__ tab)
{
    int idx = blockIdx.x * 256 + threadIdx.x;   // 0..65535
    int h = idx >> 12;
    int t = idx & 4095;
    int rp = t - 2048;          // rel_pos = k - q
    int n = -rp;                // q - k
    int ret = 0;
    if (n < 0) { ret = 16; n = -n; }
    int inner;
    if (n < 8) {
        inner = n;
    } else {
        inner = 8 + (n >= 12) + (n >= 16) + (n >= 23) + (n >= 32)
                  + (n >= 46) + (n >= 64) + (n >= 91);
        if (inner > 15) inner = 15;
    }
    tab[h * 4096 + t] = rel_emb[(ret + inner) * NH + h] * LOG2E;
}

// ---------------- X convert: fp32 -> fp16 ----------------------------------
__global__ __launch_bounds__(256) void convert_x(
    const float* __restrict__ X, u16* __restrict__ Xf)
{
    long i8 = ((long)blockIdx.x * 256 + threadIdx.x) * 8;
    float4 a = *(const float4*)&X[i8];
    float4 b = *(const float4*)&X[i8 + 4];
    *(ushort4*)&Xf[i8] =
        make_ushort4(f2h(a.x), f2h(a.y), f2h(a.z), f2h(a.w));
    *(ushort4*)&Xf[i8 + 4] =
        make_ushort4(f2h(b.x), f2h(b.y), f2h(b.z), f2h(b.w));
}

// ---------------- weight convert + transpose: W[k][n] -> WT fp16 [n][k] ----
__global__ __launch_bounds__(256) void convert_wT(
    const float* __restrict__ Wq, const float* __restrict__ Wk,
    const float* __restrict__ Wv, const float* __restrict__ Wo,
    u16* __restrict__ WT)
{
    const float* src = (blockIdx.z == 0) ? Wq : (blockIdx.z == 1) ? Wk
                     : (blockIdx.z == 2) ? Wv : Wo;
    u16* dT = WT + (long)blockIdx.z * 1048576;
    __shared__ __align__(16) float T[64 * 68];
    const int k0 = blockIdx.y * 64, n0 = blockIdx.x * 64;
    const int tid = threadIdx.x;
    #pragma unroll
    for (int u = 0; u < 4; u++) {
        int w = tid + u * 256;
        int r = w >> 4, c4 = (w & 15) * 4;
        *(float4*)&T[r * 68 + c4] =
            *(const float4*)&src[(long)(k0 + r) * DMODEL + n0 + c4];
    }
    __syncthreads();
    #pragma unroll
    for (int u = 0; u < 4; u++) {
        int w = tid + u * 256;
        int n = w >> 4, kc = (w & 15) * 4;
        *(ushort4*)&dT[(long)(n0 + n) * DMODEL + k0 + kc] = make_ushort4(
            f2h(T[(kc + 0) * 68 + n]), f2h(T[(kc + 1) * 68 + n]),
            f2h(T[(kc + 2) * 68 + n]), f2h(T[(kc + 3) * 68 + n]));
    }
}

// ------------------------- MFMA QKV GEMM (fp16, 1-pass) --------------------
// z=0: Q -> [B,H,S,Dk]; z=1: K -> [B,H,S,Dk]; z=2: V -> V^T [B,H,Dk,S].
// Double-buffered LDS: ONE barrier per K-step. Frag reads are issued before
// the commit-writes so the MFMAs wait only on the reads (partial lgkmcnt).
__global__ __launch_bounds__(256, 3) void gemm_qkv_mfma(
    const u16* __restrict__ Xf, const u16* __restrict__ WT,
    u16* __restrict__ Qf, u16* __restrict__ Kf, u16* __restrict__ VT)
{
    const int z = blockIdx.z;
    const u16* BT = WT + (long)z * 1048576;

    __shared__ __align__(16) u16 Ah[2][128 * LSTR], Bh[2][128 * LSTR];

    const int tid = threadIdx.x;
    const int wv = tid >> 6, lane = tid & 63;
    const int g = lane >> 4, li = lane & 15;
    const int wr = wv >> 1, wc = wv & 1;
    const int bm = blockIdx.y * 128, bn = blockIdx.x * 128;

    const int srow = tid >> 2, sq8 = (tid & 3) * 8;
    const u16* As0 = &Xf[(long)(bm + srow) * DMODEL + sq8];
    const u16* As1 = As0 + 64 * DMODEL;
    const u16* Bs0 = &BT[(long)(bn + srow) * DMODEL + sq8];
    const u16* Bs1 = Bs0 + 64 * DMODEL;
    const int l0 = srow * LSTR + sq8, l1 = (srow + 64) * LSTR + sq8;

    f32x4 acc[4][4];
    #pragma unroll
    for (int i = 0; i < 4; i++)
        #pragma unroll
        for (int j = 0; j < 4; j++) acc[i][j] = (f32x4){0.f, 0.f, 0.f, 0.f};

    // prologue: stage k=0 into buf0, prefetch k=32 into regs
    *(uint4*)&Ah[0][l0] = *(const uint4*)As0;
    *(uint4*)&Ah[0][l1] = *(const uint4*)As1;
    *(uint4*)&Bh[0][l0] = *(const uint4*)Bs0;
    *(uint4*)&Bh[0][l1] = *(const uint4*)Bs1;
    uint4 na0 = *(const uint4*)(As0 + 32);
    uint4 na1 = *(const uint4*)(As1 + 32);
    uint4 nb0 = *(const uint4*)(Bs0 + 32);
    uint4 nb1 = *(const uint4*)(Bs1 + 32);
    __syncthreads();

    int cur = 0;
    for (int k0 = 0; k0 < DMODEL; k0 += 32) {
        // frag reads from current buffer (issue before commit writes)
        f16x8 a_h[4], b_h[4];
        #pragma unroll
        for (int i = 0; i < 4; i++)
            a_h[i] = *(const f16x8*)&Ah[cur][(wr * 64 + i * 16 + li) * LSTR + g * 8];
        #pragma unroll
        for (int j = 0; j < 4; j++)
            b_h[j] = *(const f16x8*)&Bh[cur][(wc * 64 + j * 16 + li) * LSTR + g * 8];

        // commit prefetched k0+32 into other buffer (safe: all waves passed
        // the previous barrier, so no one still reads buf[cur^1])
        if (k0 + 32 < DMODEL) {
            *(uint4*)&Ah[cur ^ 1][l0] = na0;
            *(uint4*)&Ah[cur ^ 1][l1] = na1;
            *(uint4*)&Bh[cur ^ 1][l0] = nb0;
            *(uint4*)&Bh[cur ^ 1][l1] = nb1;
        }
        // issue k0+64 global loads
        if (k0 + 64 < DMODEL) {
            na0 = *(const uint4*)(As0 + k0 + 64);
            na1 = *(const uint4*)(As1 + k0 + 64);
            nb0 = *(const uint4*)(Bs0 + k0 + 64);
            nb1 = *(const uint4*)(Bs1 + k0 + 64);
        }

        #pragma unroll
        for (int i = 0; i < 4; i++)
            #pragma unroll
            for (int j = 0; j < 4; j++)
                acc[i][j] = __builtin_amdgcn_mfma_f32_16x16x32_f16(
                    a_h[i], b_h[j], acc[i][j], 0, 0, 0);

        __syncthreads();
        cur ^= 1;
    }

    if (z == 2) {
        // V^T epilogue: [B,H,Dk,S]; r-contiguous along S -> ushort4 stores
        #pragma unroll
        for (int i = 0; i < 4; i++) {
            int s_base = bm + wr * 64 + i * 16 + g * 4;
            int bb = s_base >> 11, s = s_base & 2047;
            #pragma unroll
            for (int j = 0; j < 4; j++) {
                int gcol = bn + wc * 64 + j * 16 + li;
                int hh = gcol >> 6, d = gcol & 63;
                long idx = (((long)(bb * NH + hh)) * DK + d) * S_LEN + s;
                *(ushort4*)&VT[idx] = make_ushort4(
                    f2h(acc[i][j][0]), f2h(acc[i][j][1]),
                    f2h(acc[i][j][2]), f2h(acc[i][j][3]));
            }
        }
    } else {
        u16* O = (z == 0) ? Qf : Kf;
        #pragma unroll
        for (int i = 0; i < 4; i++) {
            #pragma unroll
            for (int r = 0; r < 4; r++) {
                int grow = bm + wr * 64 + i * 16 + g * 4 + r;
                int bb = grow >> 11, s = grow & 2047;
                #pragma unroll
                for (int j = 0; j < 4; j++) {
                    int gcol = bn + wc * 64 + j * 16 + li;
                    int hh = gcol >> 6, d = gcol & 63;
                    long idx = (((long)(bb * NH + hh)) * S_LEN + s) * DK + d;
                    O[idx] = f2h(acc[i][j][r]);
                }
            }
        }
    }
}

// ------------------------- MFMA output GEMM (fp16) -------------------------
__global__ __launch_bounds__(256, 3) void gemm_out_mfma(
    const u16* __restrict__ Ab, const u16* __restrict__ WT,
    float* __restrict__ O)
{
    const u16* BT = WT + 3L * 1048576;   // wo fp16 plane
    __shared__ __align__(16) u16 Ah[2][128 * LSTR], Bh[2][128 * LSTR];

    const int tid = threadIdx.x;
    const int wv = tid >> 6, lane = tid & 63;
    const int g = lane >> 4, li = lane & 15;
    const int wr = wv >> 1, wc = wv & 1;
    const int bm = blockIdx.y * 128, bn = blockIdx.x * 128;

    const int srow = tid >> 2, sq8 = (tid & 3) * 8;
    const u16* As0 = &Ab[(long)(bm + srow) * DMODEL + sq8];
    const u16* As1 = As0 + 64 * DMODEL;
    const u16* Bs0 = &BT[(long)(bn + srow) * DMODEL + sq8];
    const u16* Bs1 = Bs0 + 64 * DMODEL;
    const int l0 = srow * LSTR + sq8, l1 = (srow + 64) * LSTR + sq8;

    f32x4 acc[4][4];
    #pragma unroll
    for (int i = 0; i < 4; i++)
        #pragma unroll
        for (int j = 0; j < 4; j++) acc[i][j] = (f32x4){0.f, 0.f, 0.f, 0.f};

    *(uint4*)&Ah[0][l0] = *(const uint4*)As0;
    *(uint4*)&Ah[0][l1] = *(const uint4*)As1;
    *(uint4*)&Bh[0][l0] = *(const uint4*)Bs0;
    *(uint4*)&Bh[0][l1] = *(const uint4*)Bs1;
    uint4 na0 = *(const uint4*)(As0 + 32);
    uint4 na1 = *(const uint4*)(As1 + 32);
    uint4 nb0 = *(const uint4*)(Bs0 + 32);
    uint4 nb1 = *(const uint4*)(Bs1 + 32);
    __syncthreads();

    int cur = 0;
    for (int k0 = 0; k0 < DMODEL; k0 += 32) {
        f16x8 a_h[4], b_h[4];
        #pragma unroll
        for (int i = 0; i < 4; i++)
            a_h[i] = *(const f16x8*)&Ah[cur][(wr * 64 + i * 16 + li) * LSTR + g * 8];
        #pragma unroll
        for (int j = 0; j < 4; j++)
            b_h[j] = *(const f16x8*)&Bh[cur][(wc * 64 + j * 16 + li) * LSTR + g * 8];

        if (k0 + 32 < DMODEL) {
            *(uint4*)&Ah[cur ^ 1][l0] = na0;
            *(uint4*)&Ah[cur ^ 1][l1] = na1;
            *(uint4*)&Bh[cur ^ 1][l0] = nb0;
            *(uint4*)&Bh[cur ^ 1][l1] = nb1;
        }
        if (k0 + 64 < DMODEL) {
            na0 = *(const uint4*)(As0 + k0 + 64);
            na1 = *(const uint4*)(As1 + k0 + 64);
            nb0 = *(const uint4*)(Bs0 + k0 + 64);
            nb1 = *(const uint4*)(Bs1 + k0 + 64);
        }

        #pragma unroll
        for (int i = 0; i < 4; i++)
            #pragma unroll
            for (int j = 0; j < 4; j++)
                acc[i][j] = __builtin_amdgcn_mfma_f32_16x16x32_f16(
                    a_h[i], b_h[j], acc[i][j], 0, 0, 0);

        __syncthreads();
        cur ^= 1;
    }

    #pragma unroll
    for (int i = 0; i < 4; i++)
        #pragma unroll
        for (int r = 0; r < 4; r++) {
            int grow = bm + wr * 64 + i * 16 + g * 4 + r;
            #pragma unroll
            for (int j = 0; j < 4; j++) {
                int gcol = bn + wc * 64 + j * 16 + li;
                O[(long)grow * DMODEL + gcol] = acc[i][j][r];
            }
        }
}

// ------------------------- MFMA flash attention (fp16, S^T softmax) --------
// Scores computed transposed: S^T = K·Q^T -> each lane owns ONE query.
// This version:
//  - K double-buffered in LDS -> ONE barrier per tile (was two)
//  - V read DIRECTLY from global (L2-resident w/ XCD swizzle) into MFMA regs,
//    issued at tile start so L2 latency hides under QK+softmax. No Vs in LDS.
//  - bijective XCD swizzle: each XCD owns 4 contiguous (b,h) pairs -> 2 MB
//    K/V working set fits the 4 MB per-XCD L2.
#define APAD 72

__global__ __launch_bounds__(256, 4) void attn_mfma(
    const u16* __restrict__ Qf, const u16* __restrict__ Kf,
    const u16* __restrict__ VT, const float* __restrict__ tab,
    u16* __restrict__ ctxb)
{
    __shared__ __align__(16) u16 Ks[2][64 * APAD];
    __shared__ __align__(16) u16 Ps[64 * APAD];    // [q][key], wave-private rows
    __shared__ float biasS[2][128];

    const int tid = threadIdx.x;
    const int wv = tid >> 6, lane = tid & 63;
    const int g = lane >> 4, li = lane & 15;

    // XCD-aware swizzle (1024 % 8 == 0 -> bijective): XCD x gets blocks
    // [x*128, (x+1)*128) = 4 whole (b,h) pairs.
    const int nbid = (blockIdx.x & 7) * 128 + (blockIdx.x >> 3);
    const int qblk = nbid & 31;
    const int h = (nbid >> 5) & 15;
    const int b = nbid >> 9;
    const int q0 = qblk * 64;
    const long bh = b * NH + h;
    const int qloc = wv * 16 + li;     // this lane's query (within block)

    const u16* KhG = Kf + bh * (S_LEN * DK);
    const u16* VtG = VT + bh * (DK * S_LEN);
    const float* th = tab + h * 4096;

    const int srow = tid >> 3, sc8 = (tid & 7) * 8;       // K staging coords
    const u16* Kst = KhG + (long)srow * DK + sc8;
    const u16* vpb = VtG + (long)li * S_LEN + g * 8;      // V direct base

    f16x8 q0f, q1f;
    {
        long qrow = bh * S_LEN + q0 + qloc;
        const u16* ph = Qf + qrow * DK + g * 8;
        q0f = *(const f16x8*)ph;  q1f = *(const f16x8*)(ph + 32);
    }

    // ---- prologue: stage tile 0, prefetch tile 1 into regs ----
    *(uint4*)&Ks[0][srow * APAD + sc8] = *(const uint4*)Kst;
    *(uint4*)&Ks[0][(srow + 32) * APAD + sc8] = *(const uint4*)(Kst + 32 * DK);
    if (tid < 128) {
        int idx = tid - 63 - q0 + 2048;
        idx = idx < 0 ? 0 : (idx > 4095 ? 4095 : idx);
        biasS[0][tid] = th[idx];
    }
    uint4 nk0 = *(const uint4*)(Kst + 64 * DK);
    uint4 nk1 = *(const uint4*)(Kst + 96 * DK);
    float nb = 0.f;
    if (tid < 128) {
        int idx = 64 + tid - 63 - q0 + 2048;
        idx = idx < 0 ? 0 : (idx > 4095 ? 4095 : idx);
        nb = th[idx];
    }
    __syncthreads();

    f32x4 Oc[4];
    #pragma unroll
    for (int n = 0; n < 4; n++) Oc[n] = (f32x4){0.f, 0.f, 0.f, 0.f};
    float mP = -1e30f, lR = 0.f;   // mP in log2 domain

    int cur = 0;
    for (int t = 0; t < NTILES; ++t) {
        const int kt0 = t * 64;

        // ---- V(t): issue early, direct from global (L2); consumed at PV ----
        f16x8 va[4], vb[4];
        #pragma unroll
        for (int n = 0; n < 4; n++) {
            const u16* vp = vpb + (long)n * (16 * S_LEN) + kt0;
            va[n] = *(const f16x8*)vp;
            vb[n] = *(const f16x8*)(vp + 32);
        }

        // ---- scores transposed: S^T[key][q] = K·Q^T on Ks[cur] ----
        f32x4 Sa[4];
        __builtin_amdgcn_s_setprio(1);
        #pragma unroll
        for (int m = 0; m < 4; m++) {
            const u16* kp = &Ks[cur][(m * 16 + li) * APAD + g * 8];
            f16x8 k0 = *(const f16x8*)kp, k1 = *(const f16x8*)(kp + 32);
            f32x4 s = (f32x4){0.f, 0.f, 0.f, 0.f};
            s = __builtin_amdgcn_mfma_f32_16x16x32_f16(k0, q0f, s, 0, 0, 0);
            s = __builtin_amdgcn_mfma_f32_16x16x32_f16(k1, q1f, s, 0, 0, 0);
            Sa[m] = s;   // rows: key = m*16 + g*4 + r ; col: query = li
        }
        __builtin_amdgcn_s_setprio(0);

        // ---- commit prefetched K(t+1)+bias(t+1) (other buffer; safe: all
        //      waves passed the previous barrier) ----
        if (t + 1 < NTILES) {
            *(uint4*)&Ks[cur ^ 1][srow * APAD + sc8] = nk0;
            *(uint4*)&Ks[cur ^ 1][(srow + 32) * APAD + sc8] = nk1;
            if (tid < 128) biasS[cur ^ 1][tid] = nb;
        }
        // ---- issue K(t+2)+bias(t+2) global loads ----
        if (t + 2 < NTILES) {
            const u16* kp2 = Kst + (long)(kt0 + 128) * DK;
            nk0 = *(const uint4*)kp2;
            nk1 = *(const uint4*)(kp2 + 32 * DK);
            if (tid < 128) {
                int idx = kt0 + 128 + tid - 63 - q0 + 2048;
                idx = idx < 0 ? 0 : (idx > 4095 ? 4095 : idx);
                nb = th[idx];
            }
        }

        // ---- bias add + log2e scale in one fma (table pre-scaled) ----
        #pragma unroll
        for (int m = 0; m < 4; m++)
            #pragma unroll
            for (int r = 0; r < 4; r++)
                Sa[m][r] = fmaf(Sa[m][r], LOG2E,
                                biasS[cur][m * 16 + g * 4 + r + 63 - qloc]);

        // ---- tile max: tree reduce 16 in-reg, then 2 shfl steps ----
        float mm[4];
        #pragma unroll
        for (int m = 0; m < 4; m++)
            mm[m] = fmaxf(fmaxf(Sa[m][0], Sa[m][1]),
                          fmaxf(Sa[m][2], Sa[m][3]));
        float pm = fmaxf(fmaxf(mm[0], mm[1]), fmaxf(mm[2], mm[3]));
        pm = fmaxf(pm, __shfl_xor(pm, 16));
        pm = fmaxf(pm, __shfl_xor(pm, 32));

        // ---- exact rescale-skip: alpha==1 when no query's max grew ----
        if (__any(pm > mP)) {
            float mn = fmaxf(mP, pm);
            float alpha = __builtin_amdgcn_exp2f(mP - mn);
            mP = mn;
            lR *= alpha;
            float aO[4];
            #pragma unroll
            for (int r = 0; r < 4; r++) aO[r] = __shfl(alpha, g * 4 + r);
            #pragma unroll
            for (int n = 0; n < 4; n++)
                #pragma unroll
                for (int r = 0; r < 4; r++) Oc[n][r] *= aO[r];
        }

        // ---- P = exp2(t - mP); tree-sum ----
        float sm[4];
        #pragma unroll
        for (int m = 0; m < 4; m++) {
            #pragma unroll
            for (int r = 0; r < 4; r++)
                Sa[m][r] = __builtin_amdgcn_exp2f(Sa[m][r] - mP);
            sm[m] = (Sa[m][0] + Sa[m][1]) + (Sa[m][2] + Sa[m][3]);
        }
        float ls = (sm[0] + sm[1]) + (sm[2] + sm[3]);
        ls += __shfl_xor(ls, 16);
        ls += __shfl_xor(ls, 32);
        lR += ls;

        // ---- P -> LDS [q][key], 8B stores; wave-private rows, no barrier --
        #pragma unroll
        for (int m = 0; m < 4; m++)
            *(ushort4*)&Ps[qloc * APAD + m * 16 + g * 4] = make_ushort4(
                f2h(Sa[m][0]), f2h(Sa[m][1]), f2h(Sa[m][2]), f2h(Sa[m][3]));

        // ---- O += P · V (V from regs, loaded at tile start) ----
        {
            const u16* pp = &Ps[qloc * APAD + g * 8];
            f16x8 p0 = *(const f16x8*)pp, p1 = *(const f16x8*)(pp + 32);
            __builtin_amdgcn_s_setprio(1);
            #pragma unroll
            for (int n = 0; n < 4; n++) {
                Oc[n] = __builtin_amdgcn_mfma_f32_16x16x32_f16(p0, va[n], Oc[n], 0, 0, 0);
                Oc[n] = __builtin_amdgcn_mfma_f32_16x16x32_f16(p1, vb[n], Oc[n], 0, 0, 0);
            }
            __builtin_amdgcn_s_setprio(0);
        }

        __syncthreads();   // single barrier per tile
        cur ^= 1;
    }

    float linv = 1.0f / lR;
    float iv[4];
    #pragma unroll
    for (int r = 0; r < 4; r++) iv[r] = __shfl(linv, g * 4 + r);
    #pragma unroll
    for (int n = 0; n < 4; n++)
        #pragma unroll
        for (int r = 0; r < 4; r++)
            ctxb[((long)(b * S_LEN + q0 + wv * 16 + g * 4 + r)) * DMODEL
                 + h * DK + n * 16 + li] = f2h(Oc[n][r] * iv[r]);
}

// ------------------------- launcher ----------------------------------------
extern "C" void kernel_launch(void* const* d_in, const int* in_sizes, int n_in,
                              void* d_out, int out_size, void* d_ws, size_t ws_size,
                              hipStream_t stream)
{
    const float* x    = (const float*)d_in[0];
    const float* wq   = (const float*)d_in[1];
    const float* wk   = (const float*)d_in[2];
    const float* wv   = (const float*)d_in[3];
    const float* wo   = (const float*)d_in[4];
    const float* rel  = (const float*)d_in[5];

    u16* W0 = (u16*)d_ws;
    u16* Xf  = W0;                          // fp16 x         (8 MB)
    u16* Qf  = W0 + 4194304;                // fp16 [B,H,S,Dk]
    u16* Kf  = W0 + 8388608;
    u16* VT  = W0 + 12582912;               // fp16 [B,H,Dk,S]
    u16* WT  = W0 + 16777216;               // 4 fp16 planes [n][k] (8 MB)
    float* tab = (float*)(W0 + 20971520);   // [16,4096] fp32 (pre-scaled log2e)
    u16* ctxb = Xf;                         // alias: Xf dead after gemm_qkv

    bias_table_kernel<<<dim3(256), dim3(256), 0, stream>>>(rel, tab);
    convert_x<<<dim3(2048), dim3(256), 0, stream>>>(x, Xf);
    convert_wT<<<dim3(16, 16, 4), dim3(256), 0, stream>>>(wq, wk, wv, wo, WT);
    gemm_qkv_mfma<<<dim3(8, 32, 3), dim3(256), 0, stream>>>(Xf, WT, Qf, Kf, VT);
    attn_mfma<<<dim3(1024), dim3(256), 0, stream>>>(Qf, Kf, VT, tab, ctxb);
    gemm_out_mfma<<<dim3(8, 32), dim3(256), 0, stream>>>(ctxb, WT, (float*)d_out);
}

// Round 3
// 217.338 us; speedup vs baseline: 1.2702x; 1.2702x over previous
//
#include <hip/hip_runtime.h>
#include <hip/hip_bf16.h>

typedef __attribute__((ext_vector_type(8))) _Float16 f16x8;
typedef __attribute__((ext_vector_type(4))) float f32x4;
typedef unsigned short u16;
typedef unsigned int u32;

#define S_LEN 2048
#define NH    16
#define DK    64
#define DMODEL 1024
#define LSTR  40   // LDS row stride (f16 elems) for GEMM tiles
#define LOG2E 1.44269504f
#define NTILES (S_LEN / 64)

union F16U { _Float16 h; u16 u; };
__device__ __forceinline__ u16 f2h(float f) {
    F16U v; v.h = (_Float16)f; return v.u;
}

// ------------------------- bias table --------------------------------------
// Integer-exact replica of the reference fp32 bucket math; thresholds
// {12,16,23,32,46,64,91} verified against fp32 log arithmetic.
// NOTE: table is pre-scaled by log2(e) — attn softmax runs in exp2 domain.
__global__ __launch_bounds__(256) void bias_table_kernel(
    const float* __restrict__ rel_emb, float* __restrict__ tab)
{
    int idx = blockIdx.x * 256 + threadIdx.x;   // 0..65535
    int h = idx >> 12;
    int t = idx & 4095;
    int rp = t - 2048;          // rel_pos = k - q
    int n = -rp;                // q - k
    int ret = 0;
    if (n < 0) { ret = 16; n = -n; }
    int inner;
    if (n < 8) {
        inner = n;
    } else {
        inner = 8 + (n >= 12) + (n >= 16) + (n >= 23) + (n >= 32)
                  + (n >= 46) + (n >= 64) + (n >= 91);
        if (inner > 15) inner = 15;
    }
    tab[h * 4096 + t] = rel_emb[(ret + inner) * NH + h] * LOG2E;
}

// ---------------- X convert: fp32 -> fp16 ----------------------------------
__global__ __launch_bounds__(256) void convert_x(
    const float* __restrict__ X, u16* __restrict__ Xf)
{
    long i8 = ((long)blockIdx.x * 256 + threadIdx.x) * 8;
    float4 a = *(const float4*)&X[i8];
    float4 b = *(const float4*)&X[i8 + 4];
    *(ushort4*)&Xf[i8] =
        make_ushort4(f2h(a.x), f2h(a.y), f2h(a.z), f2h(a.w));
    *(ushort4*)&Xf[i8 + 4] =
        make_ushort4(f2h(b.x), f2h(b.y), f2h(b.z), f2h(b.w));
}

// ---------------- weight convert + transpose: W[k][n] -> WT fp16 [n][k] ----
__global__ __launch_bounds__(256) void convert_wT(
    const float* __restrict__ Wq, const float* __restrict__ Wk,
    const float* __restrict__ Wv, const float* __restrict__ Wo,
    u16* __restrict__ WT)
{
    const float* src = (blockIdx.z == 0) ? Wq : (blockIdx.z == 1) ? Wk
                     : (blockIdx.z == 2) ? Wv : Wo;
    u16* dT = WT + (long)blockIdx.z * 1048576;
    __shared__ __align__(16) float T[64 * 68];
    const int k0 = blockIdx.y * 64, n0 = blockIdx.x * 64;
    const int tid = threadIdx.x;
    #pragma unroll
    for (int u = 0; u < 4; u++) {
        int w = tid + u * 256;
        int r = w >> 4, c4 = (w & 15) * 4;
        *(float4*)&T[r * 68 + c4] =
            *(const float4*)&src[(long)(k0 + r) * DMODEL + n0 + c4];
    }
    __syncthreads();
    #pragma unroll
    for (int u = 0; u < 4; u++) {
        int w = tid + u * 256;
        int n = w >> 4, kc = (w & 15) * 4;
        *(ushort4*)&dT[(long)(n0 + n) * DMODEL + k0 + kc] = make_ushort4(
            f2h(T[(kc + 0) * 68 + n]), f2h(T[(kc + 1) * 68 + n]),
            f2h(T[(kc + 2) * 68 + n]), f2h(T[(kc + 3) * 68 + n]));
    }
}

// ------------------------- MFMA QKV GEMM (fp16, 1-pass) --------------------
// z=0: Q -> [B,H,S,Dk]; z=1: K -> [B,H,S,Dk]; z=2: V -> V^T [B,H,Dk,S].
// R1-proven form: reg prefetch of next K-slice, two syncs around LDS commit.
__global__ __launch_bounds__(256, 3) void gemm_qkv_mfma(
    const u16* __restrict__ Xf, const u16* __restrict__ WT,
    u16* __restrict__ Qf, u16* __restrict__ Kf, u16* __restrict__ VT)
{
    const int z = blockIdx.z;
    const u16* BT = WT + (long)z * 1048576;

    __shared__ __align__(16) u16 Ah[128 * LSTR], Bh[128 * LSTR];

    const int tid = threadIdx.x;
    const int wv = tid >> 6, lane = tid & 63;
    const int g = lane >> 4, li = lane & 15;
    const int wr = wv >> 1, wc = wv & 1;
    const int bm = blockIdx.y * 128, bn = blockIdx.x * 128;

    const int srow = tid >> 2, sq8 = (tid & 3) * 8;
    const u16* As0 = &Xf[(long)(bm + srow) * DMODEL + sq8];
    const u16* As1 = As0 + 64 * DMODEL;
    const u16* Bs0 = &BT[(long)(bn + srow) * DMODEL + sq8];
    const u16* Bs1 = Bs0 + 64 * DMODEL;
    u16* AL0 = &Ah[srow * LSTR + sq8];
    u16* AL1 = &Ah[(srow + 64) * LSTR + sq8];
    u16* BL0 = &Bh[srow * LSTR + sq8];
    u16* BL1 = &Bh[(srow + 64) * LSTR + sq8];

    f32x4 acc[4][4];
    #pragma unroll
    for (int i = 0; i < 4; i++)
        #pragma unroll
        for (int j = 0; j < 4; j++) acc[i][j] = (f32x4){0.f, 0.f, 0.f, 0.f};

    // prologue: stage k0 = 0
    *(uint4*)AL0 = *(const uint4*)As0;
    *(uint4*)AL1 = *(const uint4*)As1;
    *(uint4*)BL0 = *(const uint4*)Bs0;
    *(uint4*)BL1 = *(const uint4*)Bs1;
    __syncthreads();

    for (int k0 = 0; k0 < DMODEL; k0 += 32) {
        const bool have = (k0 + 32) < DMODEL;
        uint4 na0, na1, nb0, nb1;
        if (have) {
            na0 = *(const uint4*)(As0 + k0 + 32);
            na1 = *(const uint4*)(As1 + k0 + 32);
            nb0 = *(const uint4*)(Bs0 + k0 + 32);
            nb1 = *(const uint4*)(Bs1 + k0 + 32);
        }

        f16x8 a_h[4], b_h[4];
        #pragma unroll
        for (int i = 0; i < 4; i++)
            a_h[i] = *(const f16x8*)&Ah[(wr * 64 + i * 16 + li) * LSTR + g * 8];
        #pragma unroll
        for (int j = 0; j < 4; j++)
            b_h[j] = *(const f16x8*)&Bh[(wc * 64 + j * 16 + li) * LSTR + g * 8];
        #pragma unroll
        for (int i = 0; i < 4; i++)
            #pragma unroll
            for (int j = 0; j < 4; j++)
                acc[i][j] = __builtin_amdgcn_mfma_f32_16x16x32_f16(
                    a_h[i], b_h[j], acc[i][j], 0, 0, 0);

        if (have) {
            __syncthreads();
            *(uint4*)AL0 = na0; *(uint4*)AL1 = na1;
            *(uint4*)BL0 = nb0; *(uint4*)BL1 = nb1;
            __syncthreads();
        }
    }

    if (z == 2) {
        // V^T epilogue: [B,H,Dk,S]; r-contiguous along S -> ushort4 stores
        #pragma unroll
        for (int i = 0; i < 4; i++) {
            int s_base = bm + wr * 64 + i * 16 + g * 4;
            int bb = s_base >> 11, s = s_base & 2047;
            #pragma unroll
            for (int j = 0; j < 4; j++) {
                int gcol = bn + wc * 64 + j * 16 + li;
                int hh = gcol >> 6, d = gcol & 63;
                long idx = (((long)(bb * NH + hh)) * DK + d) * S_LEN + s;
                *(ushort4*)&VT[idx] = make_ushort4(
                    f2h(acc[i][j][0]), f2h(acc[i][j][1]),
                    f2h(acc[i][j][2]), f2h(acc[i][j][3]));
            }
        }
    } else {
        u16* O = (z == 0) ? Qf : Kf;
        #pragma unroll
        for (int i = 0; i < 4; i++) {
            #pragma unroll
            for (int r = 0; r < 4; r++) {
                int grow = bm + wr * 64 + i * 16 + g * 4 + r;
                int bb = grow >> 11, s = grow & 2047;
                #pragma unroll
                for (int j = 0; j < 4; j++) {
                    int gcol = bn + wc * 64 + j * 16 + li;
                    int hh = gcol >> 6, d = gcol & 63;
                    long idx = (((long)(bb * NH + hh)) * S_LEN + s) * DK + d;
                    O[idx] = f2h(acc[i][j][r]);
                }
            }
        }
    }
}

// ------------------------- MFMA output GEMM (fp16) -------------------------
__global__ __launch_bounds__(256, 3) void gemm_out_mfma(
    const u16* __restrict__ Ab, const u16* __restrict__ WT,
    float* __restrict__ O)
{
    const u16* BT = WT + 3L * 1048576;   // wo fp16 plane
    __shared__ __align__(16) u16 Ah[128 * LSTR], Bh[128 * LSTR];

    const int tid = threadIdx.x;
    const int wv = tid >> 6, lane = tid & 63;
    const int g = lane >> 4, li = lane & 15;
    const int wr = wv >> 1, wc = wv & 1;
    const int bm = blockIdx.y * 128, bn = blockIdx.x * 128;

    const int srow = tid >> 2, sq8 = (tid & 3) * 8;
    const u16* As0 = &Ab[(long)(bm + srow) * DMODEL + sq8];
    const u16* As1 = As0 + 64 * DMODEL;
    const u16* Bs0 = &BT[(long)(bn + srow) * DMODEL + sq8];
    const u16* Bs1 = Bs0 + 64 * DMODEL;
    u16* AL0 = &Ah[srow * LSTR + sq8];
    u16* AL1 = &Ah[(srow + 64) * LSTR + sq8];
    u16* BL0 = &Bh[srow * LSTR + sq8];
    u16* BL1 = &Bh[(srow + 64) * LSTR + sq8];

    f32x4 acc[4][4];
    #pragma unroll
    for (int i = 0; i < 4; i++)
        #pragma unroll
        for (int j = 0; j < 4; j++) acc[i][j] = (f32x4){0.f, 0.f, 0.f, 0.f};

    *(uint4*)AL0 = *(const uint4*)As0;
    *(uint4*)AL1 = *(const uint4*)As1;
    *(uint4*)BL0 = *(const uint4*)Bs0;
    *(uint4*)BL1 = *(const uint4*)Bs1;
    __syncthreads();

    for (int k0 = 0; k0 < DMODEL; k0 += 32) {
        const bool have = (k0 + 32) < DMODEL;
        uint4 na0, na1, nb0, nb1;
        if (have) {
            na0 = *(const uint4*)(As0 + k0 + 32);
            na1 = *(const uint4*)(As1 + k0 + 32);
            nb0 = *(const uint4*)(Bs0 + k0 + 32);
            nb1 = *(const uint4*)(Bs1 + k0 + 32);
        }

        f16x8 a_h[4], b_h[4];
        #pragma unroll
        for (int i = 0; i < 4; i++)
            a_h[i] = *(const f16x8*)&Ah[(wr * 64 + i * 16 + li) * LSTR + g * 8];
        #pragma unroll
        for (int j = 0; j < 4; j++)
            b_h[j] = *(const f16x8*)&Bh[(wc * 64 + j * 16 + li) * LSTR + g * 8];
        #pragma unroll
        for (int i = 0; i < 4; i++)
            #pragma unroll
            for (int j = 0; j < 4; j++)
                acc[i][j] = __builtin_amdgcn_mfma_f32_16x16x32_f16(
                    a_h[i], b_h[j], acc[i][j], 0, 0, 0);

        if (have) {
            __syncthreads();
            *(uint4*)AL0 = na0; *(uint4*)AL1 = na1;
            *(uint4*)BL0 = nb0; *(uint4*)BL1 = nb1;
            __syncthreads();
        }
    }

    #pragma unroll
    for (int i = 0; i < 4; i++)
        #pragma unroll
        for (int r = 0; r < 4; r++) {
            int grow = bm + wr * 64 + i * 16 + g * 4 + r;
            #pragma unroll
            for (int j = 0; j < 4; j++) {
                int gcol = bn + wc * 64 + j * 16 + li;
                O[(long)grow * DMODEL + gcol] = acc[i][j][r];
            }
        }
}

// ------------------------- MFMA flash attention (fp16, S^T softmax) --------
// S^T = K·Q^T -> each lane owns ONE query (col=li), 16 keys in regs.
// R3 structure:
//  - K AND V double-buffered in LDS, ONE barrier per tile
//  - no Ps: P redistribution for the PV A-fragment done in-register via a
//    2-step lane-bit<->local-bit butterfly (shfl_xor 32 then 16), verified
//    element-wise against the LDS round-trip mapping
//  - no biasS: bias read per-lane from the L1-resident 16KB table (index
//    key-q+2048 never clamps for valid keys)
//  - XCD swizzle kept (FETCH 70.7 -> 12.6 MB in R2)
#define APAD 72

__global__ __launch_bounds__(256, 4) void attn_mfma(
    const u16* __restrict__ Qf, const u16* __restrict__ Kf,
    const u16* __restrict__ VT, const float* __restrict__ tab,
    u16* __restrict__ ctxb)
{
    __shared__ __align__(16) u16 Ks[2][64 * APAD];
    __shared__ __align__(16) u16 Vs[2][64 * APAD];   // [dim][key]

    const int tid = threadIdx.x;
    const int wv = tid >> 6, lane = tid & 63;
    const int g = lane >> 4, li = lane & 15;

    // XCD-aware swizzle (1024 % 8 == 0 -> bijective)
    const int nbid = (blockIdx.x & 7) * 128 + (blockIdx.x >> 3);
    const int qblk = nbid & 31;
    const int h = (nbid >> 5) & 15;
    const int b = nbid >> 9;
    const int q0 = qblk * 64;
    const long bh = b * NH + h;
    const int qloc = wv * 16 + li;     // this lane's query (within block)

    const u16* KhG = Kf + bh * (S_LEN * DK);
    const u16* VtG = VT + bh * (DK * S_LEN);
    // bias base: idx = key - (q0+qloc) + 2048, key = kt0 + m*16 + g*4 + r
    const float* thq = tab + h * 4096 + 2048 - q0 - qloc + g * 4;

    const int srow = tid >> 3, sc8 = (tid & 7) * 8;   // staging coords
    const u16* Kst = KhG + (long)srow * DK + sc8;
    const u16* Vst0 = VtG + (long)srow * S_LEN + sc8;
    const u16* Vst1 = VtG + (long)(srow + 32) * S_LEN + sc8;

    f16x8 q0f, q1f;
    {
        long qrow = bh * S_LEN + q0 + qloc;
        const u16* ph = Qf + qrow * DK + g * 8;
        q0f = *(const f16x8*)ph;  q1f = *(const f16x8*)(ph + 32);
    }

    // ---- prologue: stage tile 0, prefetch tile 1 into regs ----
    *(uint4*)&Ks[0][srow * APAD + sc8] = *(const uint4*)Kst;
    *(uint4*)&Ks[0][(srow + 32) * APAD + sc8] = *(const uint4*)(Kst + 32 * DK);
    *(uint4*)&Vs[0][srow * APAD + sc8] = *(const uint4*)Vst0;
    *(uint4*)&Vs[0][(srow + 32) * APAD + sc8] = *(const uint4*)Vst1;
    uint4 nk0 = *(const uint4*)(Kst + 64 * DK);
    uint4 nk1 = *(const uint4*)(Kst + 96 * DK);
    uint4 nv0 = *(const uint4*)(Vst0 + 64);
    uint4 nv1 = *(const uint4*)(Vst1 + 64);
    __syncthreads();

    f32x4 Oc[4];
    #pragma unroll
    for (int n = 0; n < 4; n++) Oc[n] = (f32x4){0.f, 0.f, 0.f, 0.f};
    float mP = -1e30f, lR = 0.f;   // mP in log2 domain

    int cur = 0;
    for (int t = 0; t < NTILES; ++t) {
        const int kt0 = t * 64;

        // ---- bias: 16 per-lane scalar loads from L1-hot table, issue early
        const float* tb = thq + kt0;
        float bia[4][4];
        #pragma unroll
        for (int m = 0; m < 4; m++)
            #pragma unroll
            for (int r = 0; r < 4; r++)
                bia[m][r] = tb[m * 16 + r];

        // ---- scores transposed: S^T[key][q] = K·Q^T on Ks[cur] ----
        f32x4 Sa[4];
        __builtin_amdgcn_s_setprio(1);
        #pragma unroll
        for (int m = 0; m < 4; m++) {
            const u16* kp = &Ks[cur][(m * 16 + li) * APAD + g * 8];
            f16x8 k0 = *(const f16x8*)kp, k1 = *(const f16x8*)(kp + 32);
            f32x4 s = (f32x4){0.f, 0.f, 0.f, 0.f};
            s = __builtin_amdgcn_mfma_f32_16x16x32_f16(k0, q0f, s, 0, 0, 0);
            s = __builtin_amdgcn_mfma_f32_16x16x32_f16(k1, q1f, s, 0, 0, 0);
            Sa[m] = s;   // rows: key = m*16 + g*4 + r ; col: query = li
        }
        __builtin_amdgcn_s_setprio(0);

        // ---- commit prefetched K/V(t+1) into other buffer (safe: barrier
        //      at end of t-1 means nobody still reads buf[cur^1]) ----
        if (t + 1 < NTILES) {
            *(uint4*)&Ks[cur ^ 1][srow * APAD + sc8] = nk0;
            *(uint4*)&Ks[cur ^ 1][(srow + 32) * APAD + sc8] = nk1;
            *(uint4*)&Vs[cur ^ 1][srow * APAD + sc8] = nv0;
            *(uint4*)&Vs[cur ^ 1][(srow + 32) * APAD + sc8] = nv1;
        }
        // ---- issue K/V(t+2) global loads ----
        if (t + 2 < NTILES) {
            const u16* kp2 = Kst + (long)(kt0 + 128) * DK;
            nk0 = *(const uint4*)kp2;
            nk1 = *(const uint4*)(kp2 + 32 * DK);
            nv0 = *(const uint4*)(Vst0 + kt0 + 128);
            nv1 = *(const uint4*)(Vst1 + kt0 + 128);
        }

        // ---- bias add + log2e scale in one fma (table pre-scaled) ----
        #pragma unroll
        for (int m = 0; m < 4; m++)
            #pragma unroll
            for (int r = 0; r < 4; r++)
                Sa[m][r] = fmaf(Sa[m][r], LOG2E, bia[m][r]);

        // ---- tile max: tree reduce 16 in-reg, then 2 shfl steps ----
        float mm[4];
        #pragma unroll
        for (int m = 0; m < 4; m++)
            mm[m] = fmaxf(fmaxf(Sa[m][0], Sa[m][1]),
                          fmaxf(Sa[m][2], Sa[m][3]));
        float pm = fmaxf(fmaxf(mm[0], mm[1]), fmaxf(mm[2], mm[3]));
        pm = fmaxf(pm, __shfl_xor(pm, 16));
        pm = fmaxf(pm, __shfl_xor(pm, 32));

        // ---- exact rescale-skip: alpha==1 when no query's max grew ----
        if (__any(pm > mP)) {
            float mn = fmaxf(mP, pm);
            float alpha = __builtin_amdgcn_exp2f(mP - mn);
            mP = mn;
            lR *= alpha;
            float aO[4];
            #pragma unroll
            for (int r = 0; r < 4; r++) aO[r] = __shfl(alpha, g * 4 + r);
            #pragma unroll
            for (int n = 0; n < 4; n++)
                #pragma unroll
                for (int r = 0; r < 4; r++) Oc[n][r] *= aO[r];
        }

        // ---- P = exp2(t - mP); tree-sum ----
        float sm[4];
        #pragma unroll
        for (int m = 0; m < 4; m++) {
            #pragma unroll
            for (int r = 0; r < 4; r++)
                Sa[m][r] = __builtin_amdgcn_exp2f(Sa[m][r] - mP);
            sm[m] = (Sa[m][0] + Sa[m][1]) + (Sa[m][2] + Sa[m][3]);
        }
        float ls = (sm[0] + sm[1]) + (sm[2] + sm[3]);
        ls += __shfl_xor(ls, 16);
        ls += __shfl_xor(ls, 32);
        lR += ls;

        // ---- in-register P redistribution (replaces Ps LDS round-trip) ----
        // pack RNE: y[m1*4 + m0*2 + c] = pack(P keys m*16+g*4+2c+{0,1})
        u32 y0, y1, y2, y3, y4, y5, y6, y7;
        {
            u32 p00 = f2h(Sa[0][0]) | ((u32)f2h(Sa[0][1]) << 16);
            u32 p01 = f2h(Sa[0][2]) | ((u32)f2h(Sa[0][3]) << 16);
            u32 p10 = f2h(Sa[1][0]) | ((u32)f2h(Sa[1][1]) << 16);
            u32 p11 = f2h(Sa[1][2]) | ((u32)f2h(Sa[1][3]) << 16);
            u32 p20 = f2h(Sa[2][0]) | ((u32)f2h(Sa[2][1]) << 16);
            u32 p21 = f2h(Sa[2][2]) | ((u32)f2h(Sa[2][3]) << 16);
            u32 p30 = f2h(Sa[3][0]) | ((u32)f2h(Sa[3][1]) << 16);
            u32 p31 = f2h(Sa[3][2]) | ((u32)f2h(Sa[3][3]) << 16);
            y0 = p00; y1 = p01; y2 = p10; y3 = p11;   // m=0,1 (local bit1=m&1)
            y4 = p20; y5 = p21; y6 = p30; y7 = p31;   // m=2,3
        }
        // step 1: swap lane-bit5 (mask 32) with local bit1
        {
            bool hi = (lane & 32) != 0;
            u32 s0 = hi ? y0 : y2, s1 = hi ? y1 : y3;
            u32 s4 = hi ? y4 : y6, s5 = hi ? y5 : y7;
            u32 r0 = __shfl_xor((int)s0, 32);
            u32 r1 = __shfl_xor((int)s1, 32);
            u32 r4 = __shfl_xor((int)s4, 32);
            u32 r5 = __shfl_xor((int)s5, 32);
            if (hi) { y0 = r0; y1 = r1; y4 = r4; y5 = r5; }
            else    { y2 = r0; y3 = r1; y6 = r4; y7 = r5; }
        }
        // step 2: swap lane-bit4 (mask 16) with local bit1
        {
            bool hi = (lane & 16) != 0;
            u32 s0 = hi ? y0 : y2, s1 = hi ? y1 : y3;
            u32 s4 = hi ? y4 : y6, s5 = hi ? y5 : y7;
            u32 r0 = __shfl_xor((int)s0, 16);
            u32 r1 = __shfl_xor((int)s1, 16);
            u32 r4 = __shfl_xor((int)s4, 16);
            u32 r5 = __shfl_xor((int)s5, 16);
            if (hi) { y0 = r0; y1 = r1; y4 = r4; y5 = r5; }
            else    { y2 = r0; y3 = r1; y6 = r4; y7 = r5; }
        }
        union { uint4 u; f16x8 h; } P0, P1;
        P0.u = make_uint4(y0, y1, y2, y3);   // A[q=li][keys g*8 + 0..7]
        P1.u = make_uint4(y4, y5, y6, y7);   // A[q=li][keys 32 + g*8 + 0..7]

        // ---- O += P · V (V from LDS, shared across waves) ----
        __builtin_amdgcn_s_setprio(1);
        #pragma unroll
        for (int n = 0; n < 4; n++) {
            const u16* vp = &Vs[cur][(n * 16 + li) * APAD + g * 8];
            f16x8 v0 = *(const f16x8*)vp, v1 = *(const f16x8*)(vp + 32);
            Oc[n] = __builtin_amdgcn_mfma_f32_16x16x32_f16(P0.h, v0, Oc[n], 0, 0, 0);
            Oc[n] = __builtin_amdgcn_mfma_f32_16x16x32_f16(P1.h, v1, Oc[n], 0, 0, 0);
        }
        __builtin_amdgcn_s_setprio(0);

        __syncthreads();   // single barrier per tile
        cur ^= 1;
    }

    float linv = 1.0f / lR;
    float iv[4];
    #pragma unroll
    for (int r = 0; r < 4; r++) iv[r] = __shfl(linv, g * 4 + r);
    #pragma unroll
    for (int n = 0; n < 4; n++)
        #pragma unroll
        for (int r = 0; r < 4; r++)
            ctxb[((long)(b * S_LEN + q0 + wv * 16 + g * 4 + r)) * DMODEL
                 + h * DK + n * 16 + li] = f2h(Oc[n][r] * iv[r]);
}

// ------------------------- launcher ----------------------------------------
extern "C" void kernel_launch(void* const* d_in, const int* in_sizes, int n_in,
                              void* d_out, int out_size, void* d_ws, size_t ws_size,
                              hipStream_t stream)
{
    const float* x    = (const float*)d_in[0];
    const float* wq   = (const float*)d_in[1];
    const float* wk   = (const float*)d_in[2];
    const float* wv   = (const float*)d_in[3];
    const float* wo   = (const float*)d_in[4];
    const float* rel  = (const float*)d_in[5];

    u16* W0 = (u16*)d_ws;
    u16* Xf  = W0;                          // fp16 x         (8 MB)
    u16* Qf  = W0 + 4194304;                // fp16 [B,H,S,Dk]
    u16* Kf  = W0 + 8388608;
    u16* VT  = W0 + 12582912;               // fp16 [B,H,Dk,S]
    u16* WT  = W0 + 16777216;               // 4 fp16 planes [n][k] (8 MB)
    float* tab = (float*)(W0 + 20971520);   // [16,4096] fp32 (pre-scaled log2e)
    u16* ctxb = Xf;                         // alias: Xf dead after gemm_qkv

    bias_table_kernel<<<dim3(256), dim3(256), 0, stream>>>(rel, tab);
    convert_x<<<dim3(2048), dim3(256), 0, stream>>>(x, Xf);
    convert_wT<<<dim3(16, 16, 4), dim3(256), 0, stream>>>(wq, wk, wv, wo, WT);
    gemm_qkv_mfma<<<dim3(8, 32, 3), dim3(256), 0, stream>>>(Xf, WT, Qf, Kf, VT);
    attn_mfma<<<dim3(1024), dim3(256), 0, stream>>>(Qf, Kf, VT, tab, ctxb);
    gemm_out_mfma<<<dim3(8, 32), dim3(256), 0, stream>>>(ctxb, WT, (float*)d_out);
}

// Round 5
// 216.746 us; speedup vs baseline: 1.2737x; 1.0027x over previous
//
#include <hip/hip_runtime.h>
#include <hip/hip_bf16.h>

typedef __attribute__((ext_vector_type(8))) _Float16 f16x8;
typedef __attribute__((ext_vector_type(4))) float f32x4;
typedef unsigned short u16;
typedef unsigned int u32;

#define S_LEN 2048
#define NH    16
#define DK    64
#define DMODEL 1024
#define LSTR  40   // LDS row stride (f16 elems) for GEMM tiles
#define LOG2E 1.44269504f
#define NTILES (S_LEN / 64)

union F16U { _Float16 h; u16 u; };
__device__ __forceinline__ u16 f2h(float f) {
    F16U v; v.h = (_Float16)f; return v.u;
}

// async global->LDS, 16B per lane, linear dest (wave-uniform base + lane*16)
__device__ __forceinline__ void gl16(const u16* g, u16* l) {
    __builtin_amdgcn_global_load_lds(
        (__attribute__((address_space(1))) void*)(u16*)g,
        (__attribute__((address_space(3))) void*)l, 16, 0, 0);
}

// ------------------------- bias table --------------------------------------
// Integer-exact replica of the reference fp32 bucket math; thresholds
// {12,16,23,32,46,64,91} verified against fp32 log arithmetic.
// NOTE: table is pre-scaled by log2(e) — attn softmax runs in exp2 domain.
__global__ __launch_bounds__(256) void bias_table_kernel(
    const float* __restrict__ rel_emb, float* __restrict__ tab)
{
    int idx = blockIdx.x * 256 + threadIdx.x;   // 0..65535
    int h = idx >> 12;
    int t = idx & 4095;
    int rp = t - 2048;          // rel_pos = k - q
    int n = -rp;                // q - k
    int ret = 0;
    if (n < 0) { ret = 16; n = -n; }
    int inner;
    if (n < 8) {
        inner = n;
    } else {
        inner = 8 + (n >= 12) + (n >= 16) + (n >= 23) + (n >= 32)
                  + (n >= 46) + (n >= 64) + (n >= 91);
        if (inner > 15) inner = 15;
    }
    tab[h * 4096 + t] = rel_emb[(ret + inner) * NH + h] * LOG2E;
}

// ---------------- X convert: fp32 -> fp16 ----------------------------------
__global__ __launch_bounds__(256) void convert_x(
    const float* __restrict__ X, u16* __restrict__ Xf)
{
    long i8 = ((long)blockIdx.x * 256 + threadIdx.x) * 8;
    float4 a = *(const float4*)&X[i8];
    float4 b = *(const float4*)&X[i8 + 4];
    *(ushort4*)&Xf[i8] =
        make_ushort4(f2h(a.x), f2h(a.y), f2h(a.z), f2h(a.w));
    *(ushort4*)&Xf[i8 + 4] =
        make_ushort4(f2h(b.x), f2h(b.y), f2h(b.z), f2h(b.w));
}

// ---------------- weight convert + transpose: W[k][n] -> WT fp16 [n][k] ----
__global__ __launch_bounds__(256) void convert_wT(
    const float* __restrict__ Wq, const float* __restrict__ Wk,
    const float* __restrict__ Wv, const float* __restrict__ Wo,
    u16* __restrict__ WT)
{
    const float* src = (blockIdx.z == 0) ? Wq : (blockIdx.z == 1) ? Wk
                     : (blockIdx.z == 2) ? Wv : Wo;
    u16* dT = WT + (long)blockIdx.z * 1048576;
    __shared__ __align__(16) float T[64 * 68];
    const int k0 = blockIdx.y * 64, n0 = blockIdx.x * 64;
    const int tid = threadIdx.x;
    #pragma unroll
    for (int u = 0; u < 4; u++) {
        int w = tid + u * 256;
        int r = w >> 4, c4 = (w & 15) * 4;
        *(float4*)&T[r * 68 + c4] =
            *(const float4*)&src[(long)(k0 + r) * DMODEL + n0 + c4];
    }
    __syncthreads();
    #pragma unroll
    for (int u = 0; u < 4; u++) {
        int w = tid + u * 256;
        int n = w >> 4, kc = (w & 15) * 4;
        *(ushort4*)&dT[(long)(n0 + n) * DMODEL + k0 + kc] = make_ushort4(
            f2h(T[(kc + 0) * 68 + n]), f2h(T[(kc + 1) * 68 + n]),
            f2h(T[(kc + 2) * 68 + n]), f2h(T[(kc + 3) * 68 + n]));
    }
}

// ------------------------- MFMA QKV GEMM (fp16, 1-pass) --------------------
// z=0: Q -> [B,H,S,Dk]; z=1: K -> [B,H,S,Dk]; z=2: V -> V^T [B,H,Dk,S].
// R1-proven form: reg prefetch of next K-slice, two syncs around LDS commit.
__global__ __launch_bounds__(256, 3) void gemm_qkv_mfma(
    const u16* __restrict__ Xf, const u16* __restrict__ WT,
    u16* __restrict__ Qf, u16* __restrict__ Kf, u16* __restrict__ VT)
{
    const int z = blockIdx.z;
    const u16* BT = WT + (long)z * 1048576;

    __shared__ __align__(16) u16 Ah[128 * LSTR], Bh[128 * LSTR];

    const int tid = threadIdx.x;
    const int wv = tid >> 6, lane = tid & 63;
    const int g = lane >> 4, li = lane & 15;
    const int wr = wv >> 1, wc = wv & 1;
    const int bm = blockIdx.y * 128, bn = blockIdx.x * 128;

    const int srow = tid >> 2, sq8 = (tid & 3) * 8;
    const u16* As0 = &Xf[(long)(bm + srow) * DMODEL + sq8];
    const u16* As1 = As0 + 64 * DMODEL;
    const u16* Bs0 = &BT[(long)(bn + srow) * DMODEL + sq8];
    const u16* Bs1 = Bs0 + 64 * DMODEL;
    u16* AL0 = &Ah[srow * LSTR + sq8];
    u16* AL1 = &Ah[(srow + 64) * LSTR + sq8];
    u16* BL0 = &Bh[srow * LSTR + sq8];
    u16* BL1 = &Bh[(srow + 64) * LSTR + sq8];

    f32x4 acc[4][4];
    #pragma unroll
    for (int i = 0; i < 4; i++)
        #pragma unroll
        for (int j = 0; j < 4; j++) acc[i][j] = (f32x4){0.f, 0.f, 0.f, 0.f};

    // prologue: stage k0 = 0
    *(uint4*)AL0 = *(const uint4*)As0;
    *(uint4*)AL1 = *(const uint4*)As1;
    *(uint4*)BL0 = *(const uint4*)Bs0;
    *(uint4*)BL1 = *(const uint4*)Bs1;
    __syncthreads();

    for (int k0 = 0; k0 < DMODEL; k0 += 32) {
        const bool have = (k0 + 32) < DMODEL;
        uint4 na0, na1, nb0, nb1;
        if (have) {
            na0 = *(const uint4*)(As0 + k0 + 32);
            na1 = *(const uint4*)(As1 + k0 + 32);
            nb0 = *(const uint4*)(Bs0 + k0 + 32);
            nb1 = *(const uint4*)(Bs1 + k0 + 32);
        }

        f16x8 a_h[4], b_h[4];
        #pragma unroll
        for (int i = 0; i < 4; i++)
            a_h[i] = *(const f16x8*)&Ah[(wr * 64 + i * 16 + li) * LSTR + g * 8];
        #pragma unroll
        for (int j = 0; j < 4; j++)
            b_h[j] = *(const f16x8*)&Bh[(wc * 64 + j * 16 + li) * LSTR + g * 8];
        #pragma unroll
        for (int i = 0; i < 4; i++)
            #pragma unroll
            for (int j = 0; j < 4; j++)
                acc[i][j] = __builtin_amdgcn_mfma_f32_16x16x32_f16(
                    a_h[i], b_h[j], acc[i][j], 0, 0, 0);

        if (have) {
            __syncthreads();
            *(uint4*)AL0 = na0; *(uint4*)AL1 = na1;
            *(uint4*)BL0 = nb0; *(uint4*)BL1 = nb1;
            __syncthreads();
        }
    }

    if (z == 2) {
        // V^T epilogue: [B,H,Dk,S]; r-contiguous along S -> ushort4 stores
        #pragma unroll
        for (int i = 0; i < 4; i++) {
            int s_base = bm + wr * 64 + i * 16 + g * 4;
            int bb = s_base >> 11, s = s_base & 2047;
            #pragma unroll
            for (int j = 0; j < 4; j++) {
                int gcol = bn + wc * 64 + j * 16 + li;
                int hh = gcol >> 6, d = gcol & 63;
                long idx = (((long)(bb * NH + hh)) * DK + d) * S_LEN + s;
                *(ushort4*)&VT[idx] = make_ushort4(
                    f2h(acc[i][j][0]), f2h(acc[i][j][1]),
                    f2h(acc[i][j][2]), f2h(acc[i][j][3]));
            }
        }
    } else {
        u16* O = (z == 0) ? Qf : Kf;
        #pragma unroll
        for (int i = 0; i < 4; i++) {
            #pragma unroll
            for (int r = 0; r < 4; r++) {
                int grow = bm + wr * 64 + i * 16 + g * 4 + r;
                int bb = grow >> 11, s = grow & 2047;
                #pragma unroll
                for (int j = 0; j < 4; j++) {
                    int gcol = bn + wc * 64 + j * 16 + li;
                    int hh = gcol >> 6, d = gcol & 63;
                    long idx = (((long)(bb * NH + hh)) * S_LEN + s) * DK + d;
                    O[idx] = f2h(acc[i][j][r]);
                }
            }
        }
    }
}

// ------------------------- MFMA output GEMM (fp16) -------------------------
__global__ __launch_bounds__(256, 3) void gemm_out_mfma(
    const u16* __restrict__ Ab, const u16* __restrict__ WT,
    float* __restrict__ O)
{
    const u16* BT = WT + 3L * 1048576;   // wo fp16 plane
    __shared__ __align__(16) u16 Ah[128 * LSTR], Bh[128 * LSTR];

    const int tid = threadIdx.x;
    const int wv = tid >> 6, lane = tid & 63;
    const int g = lane >> 4, li = lane & 15;
    const int wr = wv >> 1, wc = wv & 1;
    const int bm = blockIdx.y * 128, bn = blockIdx.x * 128;

    const int srow = tid >> 2, sq8 = (tid & 3) * 8;
    const u16* As0 = &Ab[(long)(bm + srow) * DMODEL + sq8];
    const u16* As1 = As0 + 64 * DMODEL;
    const u16* Bs0 = &BT[(long)(bn + srow) * DMODEL + sq8];
    const u16* Bs1 = Bs0 + 64 * DMODEL;
    u16* AL0 = &Ah[srow * LSTR + sq8];
    u16* AL1 = &Ah[(srow + 64) * LSTR + sq8];
    u16* BL0 = &Bh[srow * LSTR + sq8];
    u16* BL1 = &Bh[(srow + 64) * LSTR + sq8];

    f32x4 acc[4][4];
    #pragma unroll
    for (int i = 0; i < 4; i++)
        #pragma unroll
        for (int j = 0; j < 4; j++) acc[i][j] = (f32x4){0.f, 0.f, 0.f, 0.f};

    *(uint4*)AL0 = *(const uint4*)As0;
    *(uint4*)AL1 = *(const uint4*)As1;
    *(uint4*)BL0 = *(const uint4*)Bs0;
    *(uint4*)BL1 = *(const uint4*)Bs1;
    __syncthreads();

    for (int k0 = 0; k0 < DMODEL; k0 += 32) {
        const bool have = (k0 + 32) < DMODEL;
        uint4 na0, na1, nb0, nb1;
        if (have) {
            na0 = *(const uint4*)(As0 + k0 + 32);
            na1 = *(const uint4*)(As1 + k0 + 32);
            nb0 = *(const uint4*)(Bs0 + k0 + 32);
            nb1 = *(const uint4*)(Bs1 + k0 + 32);
        }

        f16x8 a_h[4], b_h[4];
        #pragma unroll
        for (int i = 0; i < 4; i++)
            a_h[i] = *(const f16x8*)&Ah[(wr * 64 + i * 16 + li) * LSTR + g * 8];
        #pragma unroll
        for (int j = 0; j < 4; j++)
            b_h[j] = *(const f16x8*)&Bh[(wc * 64 + j * 16 + li) * LSTR + g * 8];
        #pragma unroll
        for (int i = 0; i < 4; i++)
            #pragma unroll
            for (int j = 0; j < 4; j++)
                acc[i][j] = __builtin_amdgcn_mfma_f32_16x16x32_f16(
                    a_h[i], b_h[j], acc[i][j], 0, 0, 0);

        if (have) {
            __syncthreads();
            *(uint4*)AL0 = na0; *(uint4*)AL1 = na1;
            *(uint4*)BL0 = nb0; *(uint4*)BL1 = nb1;
            __syncthreads();
        }
    }

    #pragma unroll
    for (int i = 0; i < 4; i++)
        #pragma unroll
        for (int r = 0; r < 4; r++) {
            int grow = bm + wr * 64 + i * 16 + g * 4 + r;
            #pragma unroll
            for (int j = 0; j < 4; j++) {
                int gcol = bn + wc * 64 + j * 16 + li;
                O[(long)grow * DMODEL + gcol] = acc[i][j][r];
            }
        }
}

// ------------------------- MFMA flash attention (fp16, S^T softmax) --------
// S^T = K·Q^T -> each lane owns ONE query (col=li), 16 keys in regs.
// R5 = R4 with the P-exchange step 1 restored to the R3 hardware-verified
// select + shfl_xor(32) butterfly (permlane32_swap semantics were wrong).
//  - linear-swizzled Ks/Vs (64x64 f16) staged via global_load_lds 16B with
//    inverse-swizzled per-lane global source (T21)
//  - far-tile bias constants (bucket table constant for |rel|>=91)
//  - XCD swizzle, dbuf single-barrier, exact rescale-skip kept
__global__ __launch_bounds__(256, 4) void attn_mfma(
    const u16* __restrict__ Qf, const u16* __restrict__ Kf,
    const u16* __restrict__ VT, const float* __restrict__ tab,
    u16* __restrict__ ctxb)
{
    __shared__ __align__(16) u16 Ks[2][4096];   // [buf][row*64 + swz(dim)]
    __shared__ __align__(16) u16 Vs[2][4096];   // [buf][dim*64 + swz(key)]

    const int tid = threadIdx.x;
    const int wv = tid >> 6, lane = tid & 63;
    const int g = lane >> 4, li = lane & 15;

    // XCD-aware swizzle (1024 % 8 == 0 -> bijective)
    const int nbid = (blockIdx.x & 7) * 128 + (blockIdx.x >> 3);
    const int qblk = nbid & 31;
    const int h = (nbid >> 5) & 15;
    const int b = nbid >> 9;
    const int q0 = qblk * 64;
    const long bh = b * NH + h;
    const int qloc = wv * 16 + li;     // this lane's query (within block)

    const u16* KhG = Kf + bh * (S_LEN * DK);
    const u16* VtG = VT + bh * (DK * S_LEN);
    const float* th0 = tab + h * 4096;
    const float* thq = th0 + 2048 - q0 - qloc + g * 4;

    // ---- staging source (per lane) for global_load_lds chunks ----
    // chunk = 1KB = 8 rows x 128B; lane l writes linear bytes [l*16,l*16+16)
    // content dim-block = (l&7) ^ (l>>3)  (inverse of read-side XOR swizzle)
    const int sr  = lane >> 3;                 // row within chunk
    const int sd8 = ((lane & 7) ^ sr) * 8;     // u16 offset of 16B block
    const int c0 = wv * 2, c1 = wv * 2 + 1;    // this wave's chunks
    const u16* Kg0 = KhG + (long)(c0 * 8 + sr) * DK + sd8;
    const u16* Kg1 = KhG + (long)(c1 * 8 + sr) * DK + sd8;
    const u16* Vg0 = VtG + (long)(c0 * 8 + sr) * S_LEN + sd8;
    const u16* Vg1 = VtG + (long)(c1 * 8 + sr) * S_LEN + sd8;

    // ---- swizzled read offsets (u16 units), row&7 == li&7 ----
    const int sw  = (li & 7) * 8;
    const int roA = (g * 8) ^ sw;          // elems 0..31 block
    const int roB = (g * 8 + 32) ^ sw;     // elems 32..63 block
    const int rrow = li * 64;

    f16x8 q0f, q1f;
    {
        long qrow = bh * S_LEN + q0 + qloc;
        const u16* ph = Qf + qrow * DK + g * 8;
        q0f = *(const f16x8*)ph;  q1f = *(const f16x8*)(ph + 32);
    }
    const float bias_hi = th0[2048 + 512];   // bucket 31 (rel >= 91)
    const float bias_lo = th0[2048 - 512];   // bucket 15 (rel <= -91)

    // ---- prologue: stage tile 0 via async DMA ----
    gl16(Kg0, &Ks[0][c0 * 512]);
    gl16(Kg1, &Ks[0][c1 * 512]);
    gl16(Vg0, &Vs[0][c0 * 512]);
    gl16(Vg1, &Vs[0][c1 * 512]);
    __syncthreads();

    f32x4 Oc[4];
    #pragma unroll
    for (int n = 0; n < 4; n++) Oc[n] = (f32x4){0.f, 0.f, 0.f, 0.f};
    float mP = -1e30f, lR = 0.f;   // mP in log2 domain

    int cur = 0;
    for (int t = 0; t < NTILES; ++t) {
        const int kt0 = t * 64;

        // ---- issue next tile's DMA first (drained by end-of-tile barrier)
        if (t + 1 < NTILES) {
            const long ko = (long)(kt0 + 64) * DK;
            gl16(Kg0 + ko, &Ks[cur ^ 1][c0 * 512]);
            gl16(Kg1 + ko, &Ks[cur ^ 1][c1 * 512]);
            gl16(Vg0 + kt0 + 64, &Vs[cur ^ 1][c0 * 512]);
            gl16(Vg1 + kt0 + 64, &Vs[cur ^ 1][c1 * 512]);
        }

        // ---- bias: constant on far tiles (|rel| >= 91 for whole tile) ----
        float bia[4][4];
        const int dd = kt0 - q0;
        if (dd >= 192 || dd <= -192) {
            const float bc = (dd > 0) ? bias_hi : bias_lo;
            #pragma unroll
            for (int m = 0; m < 4; m++)
                #pragma unroll
                for (int r = 0; r < 4; r++) bia[m][r] = bc;
        } else {
            const float* tb = thq + kt0;
            #pragma unroll
            for (int m = 0; m < 4; m++)
                #pragma unroll
                for (int r = 0; r < 4; r++) bia[m][r] = tb[m * 16 + r];
        }

        // ---- scores transposed: S^T[key][q] = K·Q^T on Ks[cur] ----
        f32x4 Sa[4];
        __builtin_amdgcn_s_setprio(1);
        #pragma unroll
        for (int m = 0; m < 4; m++) {
            const u16* kp = &Ks[cur][m * 1024 + rrow];
            f16x8 k0 = *(const f16x8*)(kp + roA);
            f16x8 k1 = *(const f16x8*)(kp + roB);
            f32x4 s = (f32x4){0.f, 0.f, 0.f, 0.f};
            s = __builtin_amdgcn_mfma_f32_16x16x32_f16(k0, q0f, s, 0, 0, 0);
            s = __builtin_amdgcn_mfma_f32_16x16x32_f16(k1, q1f, s, 0, 0, 0);
            Sa[m] = s;   // rows: key = m*16 + g*4 + r ; col: query = li
        }
        __builtin_amdgcn_s_setprio(0);

        // ---- bias add + log2e scale in one fma (table pre-scaled) ----
        #pragma unroll
        for (int m = 0; m < 4; m++)
            #pragma unroll
            for (int r = 0; r < 4; r++)
                Sa[m][r] = fmaf(Sa[m][r], LOG2E, bia[m][r]);

        // ---- tile max: tree reduce 16 in-reg, then 2 shfl steps ----
        float mm[4];
        #pragma unroll
        for (int m = 0; m < 4; m++)
            mm[m] = fmaxf(fmaxf(Sa[m][0], Sa[m][1]),
                          fmaxf(Sa[m][2], Sa[m][3]));
        float pm = fmaxf(fmaxf(mm[0], mm[1]), fmaxf(mm[2], mm[3]));
        pm = fmaxf(pm, __shfl_xor(pm, 16));
        pm = fmaxf(pm, __shfl_xor(pm, 32));

        // ---- exact rescale-skip: alpha==1 when no query's max grew ----
        if (__any(pm > mP)) {
            float mn = fmaxf(mP, pm);
            float alpha = __builtin_amdgcn_exp2f(mP - mn);
            mP = mn;
            lR *= alpha;
            float aO[4];
            #pragma unroll
            for (int r = 0; r < 4; r++) aO[r] = __shfl(alpha, g * 4 + r);
            #pragma unroll
            for (int n = 0; n < 4; n++)
                #pragma unroll
                for (int r = 0; r < 4; r++) Oc[n][r] *= aO[r];
        }

        // ---- P = exp2(t - mP); tree-sum ----
        float sm[4];
        #pragma unroll
        for (int m = 0; m < 4; m++) {
            #pragma unroll
            for (int r = 0; r < 4; r++)
                Sa[m][r] = __builtin_amdgcn_exp2f(Sa[m][r] - mP);
            sm[m] = (Sa[m][0] + Sa[m][1]) + (Sa[m][2] + Sa[m][3]);
        }
        float ls = (sm[0] + sm[1]) + (sm[2] + sm[3]);
        ls += __shfl_xor(ls, 16);
        ls += __shfl_xor(ls, 32);
        lR += ls;

        // ---- in-register P redistribution (R3-verified butterfly) ----
        // pack RNE: y[m1 m0 c] = pack(P keys m*16+g*4+2c+{0,1})
        u32 y0, y1, y2, y3, y4, y5, y6, y7;
        {
            y0 = f2h(Sa[0][0]) | ((u32)f2h(Sa[0][1]) << 16);
            y1 = f2h(Sa[0][2]) | ((u32)f2h(Sa[0][3]) << 16);
            y2 = f2h(Sa[1][0]) | ((u32)f2h(Sa[1][1]) << 16);
            y3 = f2h(Sa[1][2]) | ((u32)f2h(Sa[1][3]) << 16);
            y4 = f2h(Sa[2][0]) | ((u32)f2h(Sa[2][1]) << 16);
            y5 = f2h(Sa[2][2]) | ((u32)f2h(Sa[2][3]) << 16);
            y6 = f2h(Sa[3][0]) | ((u32)f2h(Sa[3][1]) << 16);
            y7 = f2h(Sa[3][2]) | ((u32)f2h(Sa[3][3]) << 16);
        }
        // step 1: swap lane-bit5 (mask 32) with local bit1
        {
            bool hi = (lane & 32) != 0;
            u32 s0 = hi ? y0 : y2, s1 = hi ? y1 : y3;
            u32 s4 = hi ? y4 : y6, s5 = hi ? y5 : y7;
            u32 r0 = __shfl_xor((int)s0, 32);
            u32 r1 = __shfl_xor((int)s1, 32);
            u32 r4 = __shfl_xor((int)s4, 32);
            u32 r5 = __shfl_xor((int)s5, 32);
            if (hi) { y0 = r0; y1 = r1; y4 = r4; y5 = r5; }
            else    { y2 = r0; y3 = r1; y6 = r4; y7 = r5; }
        }
        // step 2: swap lane-bit4 (mask 16) with local bit1
        {
            bool hi = (lane & 16) != 0;
            u32 s0 = hi ? y0 : y2, s1 = hi ? y1 : y3;
            u32 s4 = hi ? y4 : y6, s5 = hi ? y5 : y7;
            u32 r0 = __shfl_xor((int)s0, 16);
            u32 r1 = __shfl_xor((int)s1, 16);
            u32 r4 = __shfl_xor((int)s4, 16);
            u32 r5 = __shfl_xor((int)s5, 16);
            if (hi) { y0 = r0; y1 = r1; y4 = r4; y5 = r5; }
            else    { y2 = r0; y3 = r1; y6 = r4; y7 = r5; }
        }
        union { uint4 u; f16x8 h; } P0, P1;
        P0.u = make_uint4(y0, y1, y2, y3);   // A[q=li][keys g*8 + 0..7]
        P1.u = make_uint4(y4, y5, y6, y7);   // A[q=li][keys 32 + g*8 + 0..7]

        // ---- O += P · V (V from LDS, swizzled reads) ----
        __builtin_amdgcn_s_setprio(1);
        #pragma unroll
        for (int n = 0; n < 4; n++) {
            const u16* vp = &Vs[cur][n * 1024 + rrow];
            f16x8 v0 = *(const f16x8*)(vp + roA);
            f16x8 v1 = *(const f16x8*)(vp + roB);
            Oc[n] = __builtin_amdgcn_mfma_f32_16x16x32_f16(P0.h, v0, Oc[n], 0, 0, 0);
            Oc[n] = __builtin_amdgcn_mfma_f32_16x16x32_f16(P1.h, v1, Oc[n], 0, 0, 0);
        }
        __builtin_amdgcn_s_setprio(0);

        __syncthreads();   // single barrier per tile; drains DMA (vmcnt)
        cur ^= 1;
    }

    float linv = 1.0f / lR;
    float iv[4];
    #pragma unroll
    for (int r = 0; r < 4; r++) iv[r] = __shfl(linv, g * 4 + r);
    #pragma unroll
    for (int n = 0; n < 4; n++)
        #pragma unroll
        for (int r = 0; r < 4; r++)
            ctxb[((long)(b * S_LEN + q0 + wv * 16 + g * 4 + r)) * DMODEL
                 + h * DK + n * 16 + li] = f2h(Oc[n][r] * iv[r]);
}

// ------------------------- launcher ----------------------------------------
extern "C" void kernel_launch(void* const* d_in, const int* in_sizes, int n_in,
                              void* d_out, int out_size, void* d_ws, size_t ws_size,
                              hipStream_t stream)
{
    const float* x    = (const float*)d_in[0];
    const float* wq   = (const float*)d_in[1];
    const float* wk   = (const float*)d_in[2];
    const float* wv   = (const float*)d_in[3];
    const float* wo   = (const float*)d_in[4];
    const float* rel  = (const float*)d_in[5];

    u16* W0 = (u16*)d_ws;
    u16* Xf  = W0;                          // fp16 x         (8 MB)
    u16* Qf  = W0 + 4194304;                // fp16 [B,H,S,Dk]
    u16* Kf  = W0 + 8388608;
    u16* VT  = W0 + 12582912;               // fp16 [B,H,Dk,S]
    u16* WT  = W0 + 16777216;               // 4 fp16 planes [n][k] (8 MB)
    float* tab = (float*)(W0 + 20971520);   // [16,4096] fp32 (pre-scaled log2e)
    u16* ctxb = Xf;                         // alias: Xf dead after gemm_qkv

    bias_table_kernel<<<dim3(256), dim3(256), 0, stream>>>(rel, tab);
    convert_x<<<dim3(2048), dim3(256), 0, stream>>>(x, Xf);
    convert_wT<<<dim3(16, 16, 4), dim3(256), 0, stream>>>(wq, wk, wv, wo, WT);
    gemm_qkv_mfma<<<dim3(8, 32, 3), dim3(256), 0, stream>>>(Xf, WT, Qf, Kf, VT);
    attn_mfma<<<dim3(1024), dim3(256), 0, stream>>>(Qf, Kf, VT, tab, ctxb);
    gemm_out_mfma<<<dim3(8, 32), dim3(256), 0, stream>>>(ctxb, WT, (float*)d_out);
}

// Round 6
// 203.927 us; speedup vs baseline: 1.3537x; 1.0629x over previous
//
#include <hip/hip_runtime.h>
#include <hip/hip_bf16.h>

typedef __attribute__((ext_vector_type(8))) _Float16 f16x8;
typedef __attribute__((ext_vector_type(4))) float f32x4;
typedef unsigned short u16;
typedef unsigned int u32;

#define S_LEN 2048
#define NH    16
#define DK    64
#define DMODEL 1024
#define LOG2E 1.44269504f
#define NTILES (S_LEN / 64)

union F16U { _Float16 h; u16 u; };
__device__ __forceinline__ u16 f2h(float f) {
    F16U v; v.h = (_Float16)f; return v.u;
}

// async global->LDS, 16B per lane, linear dest (wave-uniform base + lane*16)
__device__ __forceinline__ void gl16(const u16* g, u16* l) {
    __builtin_amdgcn_global_load_lds(
        (__attribute__((address_space(1))) void*)(u16*)g,
        (__attribute__((address_space(3))) void*)l, 16, 0, 0);
}

// ------------------------- fused prep kernel -------------------------------
// blocks [0,2048): convert X fp32->fp16
// blocks [2048,3072): convert+transpose W planes (wq,wk,wv,wo)
// blocks [3072,3328): bias table (integer-exact bucket replica, *log2e)
__global__ __launch_bounds__(256) void prep_kernel(
    const float* __restrict__ X,
    const float* __restrict__ Wq, const float* __restrict__ Wk,
    const float* __restrict__ Wv, const float* __restrict__ Wo,
    const float* __restrict__ rel_emb,
    u16* __restrict__ Xf, u16* __restrict__ WT, float* __restrict__ tab)
{
    __shared__ __align__(16) float T[64 * 68];
    const int bid = blockIdx.x;
    const int tid = threadIdx.x;

    if (bid < 2048) {
        long i8 = ((long)bid * 256 + tid) * 8;
        float4 a = *(const float4*)&X[i8];
        float4 b = *(const float4*)&X[i8 + 4];
        *(ushort4*)&Xf[i8] =
            make_ushort4(f2h(a.x), f2h(a.y), f2h(a.z), f2h(a.w));
        *(ushort4*)&Xf[i8 + 4] =
            make_ushort4(f2h(b.x), f2h(b.y), f2h(b.z), f2h(b.w));
    } else if (bid < 3072) {
        const int w0 = bid - 2048;
        const int z = w0 >> 8, rem = w0 & 255;
        const int k0 = (rem >> 4) * 64, n0 = (rem & 15) * 64;
        const float* src = (z == 0) ? Wq : (z == 1) ? Wk
                         : (z == 2) ? Wv : Wo;
        u16* dT = WT + (long)z * 1048576;
        #pragma unroll
        for (int u = 0; u < 4; u++) {
            int w = tid + u * 256;
            int r = w >> 4, c4 = (w & 15) * 4;
            *(float4*)&T[r * 68 + c4] =
                *(const float4*)&src[(long)(k0 + r) * DMODEL + n0 + c4];
        }
        __syncthreads();
        #pragma unroll
        for (int u = 0; u < 4; u++) {
            int w = tid + u * 256;
            int n = w >> 4, kc = (w & 15) * 4;
            *(ushort4*)&dT[(long)(n0 + n) * DMODEL + k0 + kc] = make_ushort4(
                f2h(T[(kc + 0) * 68 + n]), f2h(T[(kc + 1) * 68 + n]),
                f2h(T[(kc + 2) * 68 + n]), f2h(T[(kc + 3) * 68 + n]));
        }
    } else {
        int idx = (bid - 3072) * 256 + tid;   // 0..65535
        int h = idx >> 12;
        int t = idx & 4095;
        int rp = t - 2048;          // rel_pos = k - q
        int n = -rp;                // q - k
        int ret = 0;
        if (n < 0) { ret = 16; n = -n; }
        int inner;
        if (n < 8) {
            inner = n;
        } else {
            inner = 8 + (n >= 12) + (n >= 16) + (n >= 23) + (n >= 32)
                      + (n >= 46) + (n >= 64) + (n >= 91);
            if (inner > 15) inner = 15;
        }
        tab[h * 4096 + t] = rel_emb[(ret + inner) * NH + h] * LOG2E;
    }
}

// ------------------------- MFMA QKV GEMM (fp16, gload_lds) -----------------
// z=0: Q -> [B,H,S,Dk]; z=1: K -> [B,H,S,Dk]; z=2: V -> V^T [B,H,Dk,S].
// m97-style: 128x128 tile, BK=64, single LDS buffer, global_load_lds staging
// with the attn-proven XOR swizzle (linear dest, inverse-swizzled source,
// swizzled read -> 2-way max on reads = free).
__global__ __launch_bounds__(256, 3) void gemm_qkv_mfma(
    const u16* __restrict__ Xf, const u16* __restrict__ WT,
    u16* __restrict__ Qf, u16* __restrict__ Kf, u16* __restrict__ VT)
{
    const int z = blockIdx.z;
    const u16* BT = WT + (long)z * 1048576;

    __shared__ __align__(16) u16 Ah[128 * 64], Bh[128 * 64];  // 16 KB each

    const int tid = threadIdx.x;
    const int wv = tid >> 6, lane = tid & 63;
    const int g = lane >> 4, li = lane & 15;
    const int wr = wv >> 1, wc = wv & 1;
    const int bm = blockIdx.y * 128, bn = blockIdx.x * 128;

    // staging: chunk = 8 rows x 128B; wave wv owns chunks wv*4+u (u=0..3)
    // lane l -> row-in-chunk l>>3, source col-block (l&7)^(l>>3)
    const int sr = lane >> 3;
    const int sb = ((lane & 7) ^ sr) * 8;     // u16 offset of 16B block
    const u16* Asrc[4]; const u16* Bsrc[4];
    u16* Adst[4]; u16* Bdst[4];
    #pragma unroll
    for (int u = 0; u < 4; u++) {
        const int c = wv * 4 + u;
        const int row = c * 8 + sr;
        Asrc[u] = &Xf[(long)(bm + row) * DMODEL + sb];
        Bsrc[u] = &BT[(long)(bn + row) * DMODEL + sb];
        Adst[u] = &Ah[c * 512];
        Bdst[u] = &Bh[c * 512];
    }

    // frag read offsets (u16 units): row R, block j -> R*64 + (j^(R&7))*8
    int roA[4][2], roB[4][2];
    #pragma unroll
    for (int i = 0; i < 4; i++)
        #pragma unroll
        for (int ks = 0; ks < 2; ks++) {
            int RA = wr * 64 + i * 16 + li;
            int RB = wc * 64 + i * 16 + li;
            roA[i][ks] = RA * 64 + (((ks * 4 + g) ^ (li & 7)) * 8);
            roB[i][ks] = RB * 64 + (((ks * 4 + g) ^ (li & 7)) * 8);
        }

    f32x4 acc[4][4];
    #pragma unroll
    for (int i = 0; i < 4; i++)
        #pragma unroll
        for (int j = 0; j < 4; j++) acc[i][j] = (f32x4){0.f, 0.f, 0.f, 0.f};

    for (int k0 = 0; k0 < DMODEL; k0 += 64) {
        #pragma unroll
        for (int u = 0; u < 4; u++) {
            gl16(Asrc[u] + k0, Adst[u]);
            gl16(Bsrc[u] + k0, Bdst[u]);
        }
        __syncthreads();   // drains vmcnt -> staged data visible

        #pragma unroll
        for (int ks = 0; ks < 2; ks++) {
            f16x8 a_h[4], b_h[4];
            #pragma unroll
            for (int i = 0; i < 4; i++) a_h[i] = *(const f16x8*)&Ah[roA[i][ks]];
            #pragma unroll
            for (int j = 0; j < 4; j++) b_h[j] = *(const f16x8*)&Bh[roB[j][ks]];
            #pragma unroll
            for (int i = 0; i < 4; i++)
                #pragma unroll
                for (int j = 0; j < 4; j++)
                    acc[i][j] = __builtin_amdgcn_mfma_f32_16x16x32_f16(
                        a_h[i], b_h[j], acc[i][j], 0, 0, 0);
        }
        __syncthreads();   // reads done before next stage overwrites
    }

    if (z == 2) {
        // V^T epilogue: [B,H,Dk,S]; r-contiguous along S -> ushort4 stores
        #pragma unroll
        for (int i = 0; i < 4; i++) {
            int s_base = bm + wr * 64 + i * 16 + g * 4;
            int bb = s_base >> 11, s = s_base & 2047;
            #pragma unroll
            for (int j = 0; j < 4; j++) {
                int gcol = bn + wc * 64 + j * 16 + li;
                int hh = gcol >> 6, d = gcol & 63;
                long idx = (((long)(bb * NH + hh)) * DK + d) * S_LEN + s;
                *(ushort4*)&VT[idx] = make_ushort4(
                    f2h(acc[i][j][0]), f2h(acc[i][j][1]),
                    f2h(acc[i][j][2]), f2h(acc[i][j][3]));
            }
        }
    } else {
        u16* O = (z == 0) ? Qf : Kf;
        #pragma unroll
        for (int i = 0; i < 4; i++) {
            #pragma unroll
            for (int r = 0; r < 4; r++) {
                int grow = bm + wr * 64 + i * 16 + g * 4 + r;
                int bb = grow >> 11, s = grow & 2047;
                #pragma unroll
                for (int j = 0; j < 4; j++) {
                    int gcol = bn + wc * 64 + j * 16 + li;
                    int hh = gcol >> 6, d = gcol & 63;
                    long idx = (((long)(bb * NH + hh)) * S_LEN + s) * DK + d;
                    O[idx] = f2h(acc[i][j][r]);
                }
            }
        }
    }
}

// ------------------------- MFMA output GEMM (fp16, gload_lds) --------------
__global__ __launch_bounds__(256, 3) void gemm_out_mfma(
    const u16* __restrict__ Ab, const u16* __restrict__ WT,
    float* __restrict__ O)
{
    const u16* BT = WT + 3L * 1048576;   // wo fp16 plane
    __shared__ __align__(16) u16 Ah[128 * 64], Bh[128 * 64];

    const int tid = threadIdx.x;
    const int wv = tid >> 6, lane = tid & 63;
    const int g = lane >> 4, li = lane & 15;
    const int wr = wv >> 1, wc = wv & 1;
    const int bm = blockIdx.y * 128, bn = blockIdx.x * 128;

    const int sr = lane >> 3;
    const int sb = ((lane & 7) ^ sr) * 8;
    const u16* Asrc[4]; const u16* Bsrc[4];
    u16* Adst[4]; u16* Bdst[4];
    #pragma unroll
    for (int u = 0; u < 4; u++) {
        const int c = wv * 4 + u;
        const int row = c * 8 + sr;
        Asrc[u] = &Ab[(long)(bm + row) * DMODEL + sb];
        Bsrc[u] = &BT[(long)(bn + row) * DMODEL + sb];
        Adst[u] = &Ah[c * 512];
        Bdst[u] = &Bh[c * 512];
    }

    int roA[4][2], roB[4][2];
    #pragma unroll
    for (int i = 0; i < 4; i++)
        #pragma unroll
        for (int ks = 0; ks < 2; ks++) {
            int RA = wr * 64 + i * 16 + li;
            int RB = wc * 64 + i * 16 + li;
            roA[i][ks] = RA * 64 + (((ks * 4 + g) ^ (li & 7)) * 8);
            roB[i][ks] = RB * 64 + (((ks * 4 + g) ^ (li & 7)) * 8);
        }

    f32x4 acc[4][4];
    #pragma unroll
    for (int i = 0; i < 4; i++)
        #pragma unroll
        for (int j = 0; j < 4; j++) acc[i][j] = (f32x4){0.f, 0.f, 0.f, 0.f};

    for (int k0 = 0; k0 < DMODEL; k0 += 64) {
        #pragma unroll
        for (int u = 0; u < 4; u++) {
            gl16(Asrc[u] + k0, Adst[u]);
            gl16(Bsrc[u] + k0, Bdst[u]);
        }
        __syncthreads();

        #pragma unroll
        for (int ks = 0; ks < 2; ks++) {
            f16x8 a_h[4], b_h[4];
            #pragma unroll
            for (int i = 0; i < 4; i++) a_h[i] = *(const f16x8*)&Ah[roA[i][ks]];
            #pragma unroll
            for (int j = 0; j < 4; j++) b_h[j] = *(const f16x8*)&Bh[roB[j][ks]];
            #pragma unroll
            for (int i = 0; i < 4; i++)
                #pragma unroll
                for (int j = 0; j < 4; j++)
                    acc[i][j] = __builtin_amdgcn_mfma_f32_16x16x32_f16(
                        a_h[i], b_h[j], acc[i][j], 0, 0, 0);
        }
        __syncthreads();
    }

    #pragma unroll
    for (int i = 0; i < 4; i++)
        #pragma unroll
        for (int r = 0; r < 4; r++) {
            int grow = bm + wr * 64 + i * 16 + g * 4 + r;
            #pragma unroll
            for (int j = 0; j < 4; j++) {
                int gcol = bn + wc * 64 + j * 16 + li;
                O[(long)grow * DMODEL + gcol] = acc[i][j][r];
            }
        }
}

// ------------------------- MFMA flash attention (fp16, S^T softmax) --------
// R5-verified (pass, 82 µs, 0 bank conflicts) — unchanged.
__global__ __launch_bounds__(256, 4) void attn_mfma(
    const u16* __restrict__ Qf, const u16* __restrict__ Kf,
    const u16* __restrict__ VT, const float* __restrict__ tab,
    u16* __restrict__ ctxb)
{
    __shared__ __align__(16) u16 Ks[2][4096];   // [buf][row*64 + swz(dim)]
    __shared__ __align__(16) u16 Vs[2][4096];   // [buf][dim*64 + swz(key)]

    const int tid = threadIdx.x;
    const int wv = tid >> 6, lane = tid & 63;
    const int g = lane >> 4, li = lane & 15;

    // XCD-aware swizzle (1024 % 8 == 0 -> bijective)
    const int nbid = (blockIdx.x & 7) * 128 + (blockIdx.x >> 3);
    const int qblk = nbid & 31;
    const int h = (nbid >> 5) & 15;
    const int b = nbid >> 9;
    const int q0 = qblk * 64;
    const long bh = b * NH + h;
    const int qloc = wv * 16 + li;     // this lane's query (within block)

    const u16* KhG = Kf + bh * (S_LEN * DK);
    const u16* VtG = VT + bh * (DK * S_LEN);
    const float* th0 = tab + h * 4096;
    const float* thq = th0 + 2048 - q0 - qloc + g * 4;

    const int sr  = lane >> 3;                 // row within chunk
    const int sd8 = ((lane & 7) ^ sr) * 8;     // u16 offset of 16B block
    const int c0 = wv * 2, c1 = wv * 2 + 1;    // this wave's chunks
    const u16* Kg0 = KhG + (long)(c0 * 8 + sr) * DK + sd8;
    const u16* Kg1 = KhG + (long)(c1 * 8 + sr) * DK + sd8;
    const u16* Vg0 = VtG + (long)(c0 * 8 + sr) * S_LEN + sd8;
    const u16* Vg1 = VtG + (long)(c1 * 8 + sr) * S_LEN + sd8;

    // ---- swizzled read offsets (u16 units), row&7 == li&7 ----
    const int sw  = (li & 7) * 8;
    const int roA = (g * 8) ^ sw;          // elems 0..31 block
    const int roB = (g * 8 + 32) ^ sw;     // elems 32..63 block
    const int rrow = li * 64;

    f16x8 q0f, q1f;
    {
        long qrow = bh * S_LEN + q0 + qloc;
        const u16* ph = Qf + qrow * DK + g * 8;
        q0f = *(const f16x8*)ph;  q1f = *(const f16x8*)(ph + 32);
    }
    const float bias_hi = th0[2048 + 512];   // bucket 31 (rel >= 91)
    const float bias_lo = th0[2048 - 512];   // bucket 15 (rel <= -91)

    // ---- prologue: stage tile 0 via async DMA ----
    gl16(Kg0, &Ks[0][c0 * 512]);
    gl16(Kg1, &Ks[0][c1 * 512]);
    gl16(Vg0, &Vs[0][c0 * 512]);
    gl16(Vg1, &Vs[0][c1 * 512]);
    __syncthreads();

    f32x4 Oc[4];
    #pragma unroll
    for (int n = 0; n < 4; n++) Oc[n] = (f32x4){0.f, 0.f, 0.f, 0.f};
    float mP = -1e30f, lR = 0.f;   // mP in log2 domain

    int cur = 0;
    for (int t = 0; t < NTILES; ++t) {
        const int kt0 = t * 64;

        // ---- issue next tile's DMA first (drained by end-of-tile barrier)
        if (t + 1 < NTILES) {
            const long ko = (long)(kt0 + 64) * DK;
            gl16(Kg0 + ko, &Ks[cur ^ 1][c0 * 512]);
            gl16(Kg1 + ko, &Ks[cur ^ 1][c1 * 512]);
            gl16(Vg0 + kt0 + 64, &Vs[cur ^ 1][c0 * 512]);
            gl16(Vg1 + kt0 + 64, &Vs[cur ^ 1][c1 * 512]);
        }

        // ---- bias: constant on far tiles (|rel| >= 91 for whole tile) ----
        float bia[4][4];
        const int dd = kt0 - q0;
        if (dd >= 192 || dd <= -192) {
            const float bc = (dd > 0) ? bias_hi : bias_lo;
            #pragma unroll
            for (int m = 0; m < 4; m++)
                #pragma unroll
                for (int r = 0; r < 4; r++) bia[m][r] = bc;
        } else {
            const float* tb = thq + kt0;
            #pragma unroll
            for (int m = 0; m < 4; m++)
                #pragma unroll
                for (int r = 0; r < 4; r++) bia[m][r] = tb[m * 16 + r];
        }

        // ---- scores transposed: S^T[key][q] = K·Q^T on Ks[cur] ----
        f32x4 Sa[4];
        __builtin_amdgcn_s_setprio(1);
        #pragma unroll
        for (int m = 0; m < 4; m++) {
            const u16* kp = &Ks[cur][m * 1024 + rrow];
            f16x8 k0 = *(const f16x8*)(kp + roA);
            f16x8 k1 = *(const f16x8*)(kp + roB);
            f32x4 s = (f32x4){0.f, 0.f, 0.f, 0.f};
            s = __builtin_amdgcn_mfma_f32_16x16x32_f16(k0, q0f, s, 0, 0, 0);
            s = __builtin_amdgcn_mfma_f32_16x16x32_f16(k1, q1f, s, 0, 0, 0);
            Sa[m] = s;   // rows: key = m*16 + g*4 + r ; col: query = li
        }
        __builtin_amdgcn_s_setprio(0);

        // ---- bias add + log2e scale in one fma (table pre-scaled) ----
        #pragma unroll
        for (int m = 0; m < 4; m++)
            #pragma unroll
            for (int r = 0; r < 4; r++)
                Sa[m][r] = fmaf(Sa[m][r], LOG2E, bia[m][r]);

        // ---- tile max: tree reduce 16 in-reg, then 2 shfl steps ----
        float mm[4];
        #pragma unroll
        for (int m = 0; m < 4; m++)
            mm[m] = fmaxf(fmaxf(Sa[m][0], Sa[m][1]),
                          fmaxf(Sa[m][2], Sa[m][3]));
        float pm = fmaxf(fmaxf(mm[0], mm[1]), fmaxf(mm[2], mm[3]));
        pm = fmaxf(pm, __shfl_xor(pm, 16));
        pm = fmaxf(pm, __shfl_xor(pm, 32));

        // ---- exact rescale-skip: alpha==1 when no query's max grew ----
        if (__any(pm > mP)) {
            float mn = fmaxf(mP, pm);
            float alpha = __builtin_amdgcn_exp2f(mP - mn);
            mP = mn;
            lR *= alpha;
            float aO[4];
            #pragma unroll
            for (int r = 0; r < 4; r++) aO[r] = __shfl(alpha, g * 4 + r);
            #pragma unroll
            for (int n = 0; n < 4; n++)
                #pragma unroll
                for (int r = 0; r < 4; r++) Oc[n][r] *= aO[r];
        }

        // ---- P = exp2(t - mP); tree-sum ----
        float sm[4];
        #pragma unroll
        for (int m = 0; m < 4; m++) {
            #pragma unroll
            for (int r = 0; r < 4; r++)
                Sa[m][r] = __builtin_amdgcn_exp2f(Sa[m][r] - mP);
            sm[m] = (Sa[m][0] + Sa[m][1]) + (Sa[m][2] + Sa[m][3]);
        }
        float ls = (sm[0] + sm[1]) + (sm[2] + sm[3]);
        ls += __shfl_xor(ls, 16);
        ls += __shfl_xor(ls, 32);
        lR += ls;

        // ---- in-register P redistribution (R3-verified butterfly) ----
        u32 y0, y1, y2, y3, y4, y5, y6, y7;
        {
            y0 = f2h(Sa[0][0]) | ((u32)f2h(Sa[0][1]) << 16);
            y1 = f2h(Sa[0][2]) | ((u32)f2h(Sa[0][3]) << 16);
            y2 = f2h(Sa[1][0]) | ((u32)f2h(Sa[1][1]) << 16);
            y3 = f2h(Sa[1][2]) | ((u32)f2h(Sa[1][3]) << 16);
            y4 = f2h(Sa[2][0]) | ((u32)f2h(Sa[2][1]) << 16);
            y5 = f2h(Sa[2][2]) | ((u32)f2h(Sa[2][3]) << 16);
            y6 = f2h(Sa[3][0]) | ((u32)f2h(Sa[3][1]) << 16);
            y7 = f2h(Sa[3][2]) | ((u32)f2h(Sa[3][3]) << 16);
        }
        // step 1: swap lane-bit5 (mask 32) with local bit1
        {
            bool hi = (lane & 32) != 0;
            u32 s0 = hi ? y0 : y2, s1 = hi ? y1 : y3;
            u32 s4 = hi ? y4 : y6, s5 = hi ? y5 : y7;
            u32 r0 = __shfl_xor((int)s0, 32);
            u32 r1 = __shfl_xor((int)s1, 32);
            u32 r4 = __shfl_xor((int)s4, 32);
            u32 r5 = __shfl_xor((int)s5, 32);
            if (hi) { y0 = r0; y1 = r1; y4 = r4; y5 = r5; }
            else    { y2 = r0; y3 = r1; y6 = r4; y7 = r5; }
        }
        // step 2: swap lane-bit4 (mask 16) with local bit1
        {
            bool hi = (lane & 16) != 0;
            u32 s0 = hi ? y0 : y2, s1 = hi ? y1 : y3;
            u32 s4 = hi ? y4 : y6, s5 = hi ? y5 : y7;
            u32 r0 = __shfl_xor((int)s0, 16);
            u32 r1 = __shfl_xor((int)s1, 16);
            u32 r4 = __shfl_xor((int)s4, 16);
            u32 r5 = __shfl_xor((int)s5, 16);
            if (hi) { y0 = r0; y1 = r1; y4 = r4; y5 = r5; }
            else    { y2 = r0; y3 = r1; y6 = r4; y7 = r5; }
        }
        union { uint4 u; f16x8 h; } P0, P1;
        P0.u = make_uint4(y0, y1, y2, y3);   // A[q=li][keys g*8 + 0..7]
        P1.u = make_uint4(y4, y5, y6, y7);   // A[q=li][keys 32 + g*8 + 0..7]

        // ---- O += P · V (V from LDS, swizzled reads) ----
        __builtin_amdgcn_s_setprio(1);
        #pragma unroll
        for (int n = 0; n < 4; n++) {
            const u16* vp = &Vs[cur][n * 1024 + rrow];
            f16x8 v0 = *(const f16x8*)(vp + roA);
            f16x8 v1 = *(const f16x8*)(vp + roB);
            Oc[n] = __builtin_amdgcn_mfma_f32_16x16x32_f16(P0.h, v0, Oc[n], 0, 0, 0);
            Oc[n] = __builtin_amdgcn_mfma_f32_16x16x32_f16(P1.h, v1, Oc[n], 0, 0, 0);
        }
        __builtin_amdgcn_s_setprio(0);

        __syncthreads();   // single barrier per tile; drains DMA (vmcnt)
        cur ^= 1;
    }

    float linv = 1.0f / lR;
    float iv[4];
    #pragma unroll
    for (int r = 0; r < 4; r++) iv[r] = __shfl(linv, g * 4 + r);
    #pragma unroll
    for (int n = 0; n < 4; n++)
        #pragma unroll
        for (int r = 0; r < 4; r++)
            ctxb[((long)(b * S_LEN + q0 + wv * 16 + g * 4 + r)) * DMODEL
                 + h * DK + n * 16 + li] = f2h(Oc[n][r] * iv[r]);
}

// ------------------------- launcher ----------------------------------------
extern "C" void kernel_launch(void* const* d_in, const int* in_sizes, int n_in,
                              void* d_out, int out_size, void* d_ws, size_t ws_size,
                              hipStream_t stream)
{
    const float* x    = (const float*)d_in[0];
    const float* wq   = (const float*)d_in[1];
    const float* wk   = (const float*)d_in[2];
    const float* wv   = (const float*)d_in[3];
    const float* wo   = (const float*)d_in[4];
    const float* rel  = (const float*)d_in[5];

    u16* W0 = (u16*)d_ws;
    u16* Xf  = W0;                          // fp16 x         (8 MB)
    u16* Qf  = W0 + 4194304;                // fp16 [B,H,S,Dk]
    u16* Kf  = W0 + 8388608;
    u16* VT  = W0 + 12582912;               // fp16 [B,H,Dk,S]
    u16* WT  = W0 + 16777216;               // 4 fp16 planes [n][k] (8 MB)
    float* tab = (float*)(W0 + 20971520);   // [16,4096] fp32 (pre-scaled log2e)
    u16* ctxb = Xf;                         // alias: Xf dead after gemm_qkv

    prep_kernel<<<dim3(3328), dim3(256), 0, stream>>>(
        x, wq, wk, wv, wo, rel, Xf, WT, tab);
    gemm_qkv_mfma<<<dim3(8, 32, 3), dim3(256), 0, stream>>>(Xf, WT, Qf, Kf, VT);
    attn_mfma<<<dim3(1024), dim3(256), 0, stream>>>(Qf, Kf, VT, tab, ctxb);
    gemm_out_mfma<<<dim3(8, 32), dim3(256), 0, stream>>>(ctxb, WT, (float*)d_out);
}